// Round 1
// baseline (13878.914 us; speedup 1.0000x reference)
//
#include <hip/hip_runtime.h>
#include <cstdint>

#define T_ 32
#define N_ 5000
#define E_ 80000
#define H_ 128
#define HD_ 512
#define C_ 10

// ---------------- degree / dinv ----------------
__global__ __launch_bounds__(256) void k_init_deg(float* deg) {
    int i = blockIdx.x * 256 + threadIdx.x;
    if (i < T_ * N_) deg[i] = 1.0f;  // self-loop
}

__global__ __launch_bounds__(256) void k_count(const int* __restrict__ ei, float* deg) {
    int e = blockIdx.x * 256 + threadIdx.x;
    int t = blockIdx.y;
    if (e < E_) {
        int d = ei[(size_t)t * 2 * E_ + E_ + e];
        atomicAdd(&deg[t * N_ + d], 1.0f);
    }
}

__global__ __launch_bounds__(256) void k_rsqrt(float* deg) {
    int i = blockIdx.x * 256 + threadIdx.x;
    if (i < T_ * N_) deg[i] = rsqrtf(deg[i]);
}

// ---------------- GEMM: g[t][r][c] = dinv[t][r] * sum_k in[t][r][k]*W[k][c] ----------------
// block: 64 rows x 128 cols, 256 threads, per-thread 8x4, K chunked by 32
__global__ __launch_bounds__(256) void k_gemm(const float* __restrict__ in,
                                              const float* __restrict__ W,
                                              const float* __restrict__ dinv,
                                              float* __restrict__ g) {
    __shared__ float Ws[32 * 128];   // [k][c]
    __shared__ float As[32 * 68];    // [k][r], padded
    int t = blockIdx.y;
    int r0 = blockIdx.x * 64;
    int tid = threadIdx.x;
    int nrows = N_ - r0; if (nrows > 64) nrows = 64;
    const float* Ain = in + ((size_t)t * N_ + r0) * H_;
    int tr = tid >> 5, tc = tid & 31;
    int rr = tr * 8, cc = tc * 4;
    float acc[8][4];
#pragma unroll
    for (int i = 0; i < 8; ++i)
#pragma unroll
        for (int j = 0; j < 4; ++j) acc[i][j] = 0.0f;

    for (int kb = 0; kb < 4; ++kb) {
        for (int i = tid * 4; i < 32 * 128; i += 1024)
            *(float4*)&Ws[i] = *(const float4*)&W[kb * 4096 + i];
        for (int i = tid; i < 512; i += 256) {
            int r = i >> 3, kq = (i & 7) * 4;
            float4 v = make_float4(0.f, 0.f, 0.f, 0.f);
            if (r < nrows) v = *(const float4*)&Ain[r * H_ + kb * 32 + kq];
            As[(kq + 0) * 68 + r] = v.x;
            As[(kq + 1) * 68 + r] = v.y;
            As[(kq + 2) * 68 + r] = v.z;
            As[(kq + 3) * 68 + r] = v.w;
        }
        __syncthreads();
#pragma unroll
        for (int k = 0; k < 32; ++k) {
            float4 a0 = *(const float4*)&As[k * 68 + rr];
            float4 a1 = *(const float4*)&As[k * 68 + rr + 4];
            float4 w  = *(const float4*)&Ws[k * 128 + cc];
            float av[8] = {a0.x, a0.y, a0.z, a0.w, a1.x, a1.y, a1.z, a1.w};
            float wv[4] = {w.x, w.y, w.z, w.w};
#pragma unroll
            for (int i = 0; i < 8; ++i)
#pragma unroll
                for (int j = 0; j < 4; ++j) acc[i][j] += av[i] * wv[j];
        }
        __syncthreads();
    }
#pragma unroll
    for (int i = 0; i < 8; ++i) {
        int r = rr + i;
        if (r < nrows) {
            float d = dinv[t * N_ + r0 + r];
            float4 o = make_float4(acc[i][0] * d, acc[i][1] * d, acc[i][2] * d, acc[i][3] * d);
            *(float4*)&g[((size_t)t * N_ + r0 + r) * H_ + cc] = o;
        }
    }
}

// ---------------- edge scatter: acc[d] += g[s] ----------------
__global__ __launch_bounds__(256) void k_edges(const int* __restrict__ ei,
                                               const float* __restrict__ g,
                                               float* __restrict__ acc) {
    int tid = blockIdx.x * 256 + threadIdx.x;  // E_*32 threads per graph
    int t = blockIdx.y;
    int e = tid >> 5;
    int c = (tid & 31) * 4;
    int s = ei[(size_t)t * 2 * E_ + e];
    int d = ei[(size_t)t * 2 * E_ + E_ + e];
    float4 v = *(const float4*)&g[((size_t)t * N_ + s) * H_ + c];
    float* ap = acc + ((size_t)t * N_ + d) * H_ + c;
    atomicAdd(ap + 0, v.x);
    atomicAdd(ap + 1, v.y);
    atomicAdd(ap + 2, v.z);
    atomicAdd(ap + 3, v.w);
}

// ---------------- finish: acc = tanh(dinv*(acc + g) + b) in place ----------------
__global__ __launch_bounds__(256) void k_finish(const float* __restrict__ g,
                                                float* __restrict__ acc,
                                                const float* __restrict__ dinv,
                                                const float* __restrict__ b) {
    size_t i4 = ((size_t)blockIdx.x * 256 + threadIdx.x) * 4;
    int row = (int)(i4 >> 7);
    int c = (int)(i4 & 127);
    float d = dinv[row];
    float4 a = *(const float4*)&acc[i4];
    float4 gg = *(const float4*)&g[i4];
    float4 o;
    o.x = tanhf(d * (a.x + gg.x) + b[c + 0]);
    o.y = tanhf(d * (a.y + gg.y) + b[c + 1]);
    o.z = tanhf(d * (a.z + gg.z) + b[c + 2]);
    o.w = tanhf(d * (a.w + gg.w) + b[c + 3]);
    *(float4*)&acc[i4] = o;
}

// ---------------- node-sum: z[t][c] = sum_n h[t][n][c] ----------------
__global__ __launch_bounds__(256) void k_zinit(float* z) {
    int i = blockIdx.x * 256 + threadIdx.x;
    if (i < T_ * H_) z[i] = 0.0f;
}

__global__ __launch_bounds__(128) void k_reduce(const float* __restrict__ h, float* z) {
    int t = blockIdx.x, seg = blockIdx.y, c = threadIdx.x;
    int n0 = seg * 313;
    int n1 = n0 + 313; if (n1 > N_) n1 = N_;
    const float* p = h + (size_t)t * N_ * H_ + c;
    float s = 0.0f;
    for (int n = n0; n < n1; ++n) s += p[(size_t)n * H_];
    atomicAdd(&z[t * H_ + c], s);
}

// ---------------- head: attention + MLP + LN + pool + linear ----------------
__global__ __launch_bounds__(256) void k_head(
    const float* __restrict__ z,
    const float* __restrict__ Wq, const float* __restrict__ bq,
    const float* __restrict__ Wk, const float* __restrict__ bk,
    const float* __restrict__ Wv, const float* __restrict__ bv,
    const float* __restrict__ Wo, const float* __restrict__ bo,
    const float* __restrict__ g2, const float* __restrict__ beta2,
    const float* __restrict__ Wm1, const float* __restrict__ bm1,
    const float* __restrict__ Wm2, const float* __restrict__ bm2,
    const float* __restrict__ Wl, const float* __restrict__ bl,
    float* __restrict__ out) {
    __shared__ float S0[32 * 128];  // z, then o, then pooled/mu/rs scratch
    __shared__ float S1[32 * 128];  // q, then x_attend
    __shared__ float S2[32 * 128];  // k, then mlp hidden (8x512)
    __shared__ float S3[32 * 128];  // v, then x_attend+mlp
    int tid = threadIdx.x;

    for (int i = tid; i < 32 * 128; i += 256) S0[i] = z[i];
    __syncthreads();

    // q,k,v
    for (int i = tid; i < 32 * 128; i += 256) {
        int t = i >> 7, c = i & 127;
        float aq = bq[c], ak = bk[c], av = bv[c];
        for (int k = 0; k < 128; ++k) {
            float zv = S0[(t << 7) + k];
            aq += zv * Wq[(k << 7) + c];
            ak += zv * Wk[(k << 7) + c];
            av += zv * Wv[(k << 7) + c];
        }
        S1[i] = aq; S2[i] = ak; S3[i] = av;
    }
    __syncthreads();

    // attention: one thread per (head, t)
    {
        int h = tid >> 5, t = tid & 31;
        float sc[32];
        float m = -1e30f;
        for (int s = 0; s < 32; ++s) {
            float d = 0.0f;
#pragma unroll
            for (int k = 0; k < 16; ++k)
                d += S1[(t << 7) + (h << 4) + k] * S2[(s << 7) + (h << 4) + k];
            d *= 0.25f;  // 1/sqrt(16)
            sc[s] = d;
            m = fmaxf(m, d);
        }
        float l = 0.0f;
        for (int s = 0; s < 32; ++s) { sc[s] = __expf(sc[s] - m); l += sc[s]; }
        float inv = 1.0f / l;
        float o[16];
#pragma unroll
        for (int d = 0; d < 16; ++d) o[d] = 0.0f;
        for (int s = 0; s < 32; ++s) {
            float a = sc[s] * inv;
#pragma unroll
            for (int d = 0; d < 16; ++d) o[d] += a * S3[(s << 7) + (h << 4) + d];
        }
#pragma unroll
        for (int d = 0; d < 16; ++d) S0[(t << 7) + (h << 4) + d] = o[d];
    }
    __syncthreads();

    // x_attend = o @ Wo + bo -> S1
    for (int i = tid; i < 32 * 128; i += 256) {
        int t = i >> 7, c = i & 127;
        float a = bo[c];
        for (int k = 0; k < 128; ++k) a += S0[(t << 7) + k] * Wo[(k << 7) + c];
        S1[i] = a;
    }
    __syncthreads();

    // MLP in 4 chunks of 8 rows: hid in S2, result (xa + mlp) -> S3
    for (int ch = 0; ch < 4; ++ch) {
        for (int i = tid; i < 8 * 512; i += 256) {
            int r = i >> 9, j = i & 511;
            int t = ch * 8 + r;
            float a = bm1[j];
            for (int k = 0; k < 128; ++k) a += S1[(t << 7) + k] * Wm1[(k << 9) + j];
            S2[i] = fmaxf(a, 0.0f);
        }
        __syncthreads();
        for (int i = tid; i < 8 * 128; i += 256) {
            int r = i >> 7, c = i & 127;
            int t = ch * 8 + r;
            float a = bm2[c];
            for (int j = 0; j < 512; ++j) a += S2[(r << 9) + j] * Wm2[(j << 7) + c];
            S3[(t << 7) + c] = S1[(t << 7) + c] + a;
        }
        __syncthreads();
    }

    // LayerNorm + relu + pool + final linear (reuse S0 for scratch)
    float* pooled = S0;         // [128]
    float* mu_s = S0 + 128;     // [32]
    float* rs_s = S0 + 160;     // [32]
    if (tid < 32) {
        float s = 0.0f, s2 = 0.0f;
        for (int c = 0; c < 128; ++c) {
            float v = S3[(tid << 7) + c];
            s += v; s2 += v * v;
        }
        float mu = s * (1.0f / 128.0f);
        float var = s2 * (1.0f / 128.0f) - mu * mu;
        mu_s[tid] = mu;
        rs_s[tid] = rsqrtf(var + 1e-5f);
    }
    if (tid < 128) pooled[tid] = 0.0f;
    __syncthreads();
    for (int i = tid; i < 32 * 128; i += 256) {
        int t = i >> 7, c = i & 127;
        float v = (S3[i] - mu_s[t]) * rs_s[t] * g2[c] + beta2[c];
        v = fmaxf(v, 0.0f);
        atomicAdd(&pooled[c], v);
    }
    __syncthreads();
    if (tid < C_) {
        float a = bl[tid];
        for (int k = 0; k < 128; ++k) a += pooled[k] * Wl[k * C_ + tid];
        out[tid] = a;
    }
}

extern "C" void kernel_launch(void* const* d_in, const int* in_sizes, int n_in,
                              void* d_out, int out_size, void* d_ws, size_t ws_size,
                              hipStream_t stream) {
    const float* x  = (const float*)d_in[0];
    const int*   ei = (const int*)d_in[1];
    const float* W0 = (const float*)d_in[2];  const float* b0 = (const float*)d_in[3];
    const float* W1 = (const float*)d_in[4];  const float* b1 = (const float*)d_in[5];
    const float* W2 = (const float*)d_in[6];  const float* b2 = (const float*)d_in[7];
    const float* Wq = (const float*)d_in[8];  const float* bq = (const float*)d_in[9];
    const float* Wk = (const float*)d_in[10]; const float* bk = (const float*)d_in[11];
    const float* Wv = (const float*)d_in[12]; const float* bv = (const float*)d_in[13];
    const float* Wo = (const float*)d_in[14]; const float* bo = (const float*)d_in[15];
    const float* g2 = (const float*)d_in[16]; const float* beta2 = (const float*)d_in[17];
    const float* Wm1 = (const float*)d_in[18]; const float* bm1 = (const float*)d_in[19];
    const float* Wm2 = (const float*)d_in[20]; const float* bm2 = (const float*)d_in[21];
    const float* Wl = (const float*)d_in[22]; const float* bl = (const float*)d_in[23];
    float* outp = (float*)d_out;

    const size_t BIG = (size_t)T_ * N_ * H_;  // 20,480,000 floats
    float* ws = (float*)d_ws;
    float* dinv = ws;                 // T_*N_ = 160000 floats
    float* P = ws + 160000;           // BIG
    float* Q = P + BIG;               // BIG
    float* z = Q + BIG;               // T_*H_ = 4096

    // degrees -> dinv
    k_init_deg<<<(T_ * N_ + 255) / 256, 256, 0, stream>>>(dinv);
    k_count<<<dim3((E_ + 255) / 256, T_), 256, 0, stream>>>(ei, dinv);
    k_rsqrt<<<(T_ * N_ + 255) / 256, 256, 0, stream>>>(dinv);

    const float* Wl_[3] = {W0, W1, W2};
    const float* bl_[3] = {b0, b1, b2};
    const float* cur = x;
    for (int l = 0; l < 3; ++l) {
        k_gemm<<<dim3(79, T_), 256, 0, stream>>>(cur, Wl_[l], dinv, P);
        hipMemsetAsync(Q, 0, BIG * sizeof(float), stream);
        k_edges<<<dim3(E_ * 32 / 256, T_), 256, 0, stream>>>(ei, P, Q);
        k_finish<<<(int)(BIG / 1024), 256, 0, stream>>>(P, Q, dinv, bl_[l]);
        cur = Q;
    }

    k_zinit<<<(T_ * H_ + 255) / 256, 256, 0, stream>>>(z);
    k_reduce<<<dim3(T_, 16), 128, 0, stream>>>(Q, z);

    k_head<<<1, 256, 0, stream>>>(z, Wq, bq, Wk, bk, Wv, bv, Wo, bo,
                                  g2, beta2, Wm1, bm1, Wm2, bm2, Wl, bl, outp);
}

// Round 2
// 1688.079 us; speedup vs baseline: 8.2217x; 8.2217x over previous
//
#include <hip/hip_runtime.h>
#include <cstdint>

#define T_ 32
#define N_ 5000
#define E_ 80000
#define H_ 128
#define HD_ 512
#define C_ 10

// ---------------- CSR build ----------------
// ptr[] used as: counts -> (scan) exclusive starts -> (scatter) ends
__global__ __launch_bounds__(256) void k_count(const int* __restrict__ ei, int* __restrict__ ptr) {
    int e = blockIdx.x * 256 + threadIdx.x;
    int t = blockIdx.y;
    if (e < E_) {
        int d = ei[(size_t)t * 2 * E_ + E_ + e];
        atomicAdd(&ptr[t * N_ + d], 1);
    }
}

// one block per graph: exclusive prefix-sum of 5000 counts; also dinv = rsqrt(count+1)
__global__ __launch_bounds__(256) void k_scan(int* __restrict__ ptr, float* __restrict__ dinv) {
    int t = blockIdx.x, tid = threadIdx.x;
    __shared__ int part[256];
    int base = t * N_;
    int vals[20];
    int sum = 0;
#pragma unroll
    for (int j = 0; j < 20; ++j) {
        int i = tid * 20 + j;
        int c = 0;
        if (i < N_) {
            c = ptr[base + i];
            dinv[base + i] = rsqrtf((float)(c + 1));  // +1 self-loop
        }
        vals[j] = sum;
        sum += c;
    }
    part[tid] = sum;
    __syncthreads();
    for (int off = 1; off < 256; off <<= 1) {
        int v = (tid >= off) ? part[tid - off] : 0;
        __syncthreads();
        part[tid] += v;
        __syncthreads();
    }
    int prev = (tid > 0) ? part[tid - 1] : 0;
#pragma unroll
    for (int j = 0; j < 20; ++j) {
        int i = tid * 20 + j;
        if (i < N_) ptr[base + i] = prev + vals[j];
    }
}

__global__ __launch_bounds__(256) void k_scatter(const int* __restrict__ ei,
                                                 int* __restrict__ ptr,
                                                 uint16_t* __restrict__ col) {
    int e = blockIdx.x * 256 + threadIdx.x;
    int t = blockIdx.y;
    if (e < E_) {
        int s = ei[(size_t)t * 2 * E_ + e];
        int d = ei[(size_t)t * 2 * E_ + E_ + e];
        int pos = atomicAdd(&ptr[t * N_ + d], 1);
        col[(size_t)t * E_ + pos] = (uint16_t)s;
    }
}

// ---------------- GEMM: g[t][r][c] = dinv[t][r] * sum_k in[t][r][k]*W[k][c] ----------------
__global__ __launch_bounds__(256) void k_gemm(const float* __restrict__ in,
                                              const float* __restrict__ W,
                                              const float* __restrict__ dinv,
                                              float* __restrict__ g) {
    __shared__ float Ws[32 * 128];   // [k][c]
    __shared__ float As[32 * 68];    // [k][r], padded
    int t = blockIdx.y;
    int r0 = blockIdx.x * 64;
    int tid = threadIdx.x;
    int nrows = N_ - r0; if (nrows > 64) nrows = 64;
    const float* Ain = in + ((size_t)t * N_ + r0) * H_;
    int tr = tid >> 5, tc = tid & 31;
    int rr = tr * 8, cc = tc * 4;
    float acc[8][4];
#pragma unroll
    for (int i = 0; i < 8; ++i)
#pragma unroll
        for (int j = 0; j < 4; ++j) acc[i][j] = 0.0f;

    for (int kb = 0; kb < 4; ++kb) {
        for (int i = tid * 4; i < 32 * 128; i += 1024)
            *(float4*)&Ws[i] = *(const float4*)&W[kb * 4096 + i];
        for (int i = tid; i < 512; i += 256) {
            int r = i >> 3, kq = (i & 7) * 4;
            float4 v = make_float4(0.f, 0.f, 0.f, 0.f);
            if (r < nrows) v = *(const float4*)&Ain[r * H_ + kb * 32 + kq];
            As[(kq + 0) * 68 + r] = v.x;
            As[(kq + 1) * 68 + r] = v.y;
            As[(kq + 2) * 68 + r] = v.z;
            As[(kq + 3) * 68 + r] = v.w;
        }
        __syncthreads();
#pragma unroll
        for (int k = 0; k < 32; ++k) {
            float4 a0 = *(const float4*)&As[k * 68 + rr];
            float4 a1 = *(const float4*)&As[k * 68 + rr + 4];
            float4 w  = *(const float4*)&Ws[k * 128 + cc];
            float av[8] = {a0.x, a0.y, a0.z, a0.w, a1.x, a1.y, a1.z, a1.w};
            float wv[4] = {w.x, w.y, w.z, w.w};
#pragma unroll
            for (int i = 0; i < 8; ++i)
#pragma unroll
                for (int j = 0; j < 4; ++j) acc[i][j] += av[i] * wv[j];
        }
        __syncthreads();
    }
#pragma unroll
    for (int i = 0; i < 8; ++i) {
        int r = rr + i;
        if (r < nrows) {
            float d = dinv[t * N_ + r0 + r];
            float4 o = make_float4(acc[i][0] * d, acc[i][1] * d, acc[i][2] * d, acc[i][3] * d);
            *(float4*)&g[((size_t)t * N_ + r0 + r) * H_ + cc] = o;
        }
    }
}

// ---------------- CSR gather + epilogue: out[n] = tanh(dinv[n]*(g[n] + sum_s g[s]) + b) ----------------
// one wave per destination node; 64 lanes x float2 = 128 features
__global__ __launch_bounds__(256) void k_aggr(const int* __restrict__ ptr,
                                              const uint16_t* __restrict__ col,
                                              const float* __restrict__ g,
                                              const float* __restrict__ dinv,
                                              const float* __restrict__ b,
                                              float* __restrict__ out) {
    int t = blockIdx.y;
    int n = blockIdx.x * 4 + (threadIdx.x >> 6);
    int lane = threadIdx.x & 63;
    int c = lane * 2;
    int base = t * N_;
    int begin = (n == 0) ? 0 : ptr[base + n - 1];
    int end = ptr[base + n];
    const float* gg = g + (size_t)base * H_;
    const uint16_t* cl = col + (size_t)t * E_;
    float2 acc = *(const float2*)&gg[(size_t)n * H_ + c];  // self-loop
    for (int i = begin; i < end; ++i) {
        int s = cl[i];
        float2 v = *(const float2*)&gg[(size_t)s * H_ + c];
        acc.x += v.x;
        acc.y += v.y;
    }
    float d = dinv[base + n];
    float2 o;
    o.x = tanhf(d * acc.x + b[c + 0]);
    o.y = tanhf(d * acc.y + b[c + 1]);
    *(float2*)&out[((size_t)base + n) * H_ + c] = o;
}

// ---------------- node-sum: z[t][c] = sum_n h[t][n][c] ----------------
__global__ __launch_bounds__(256) void k_zinit(float* z) {
    int i = blockIdx.x * 256 + threadIdx.x;
    if (i < T_ * H_) z[i] = 0.0f;
}

__global__ __launch_bounds__(128) void k_reduce(const float* __restrict__ h, float* z) {
    int t = blockIdx.x, seg = blockIdx.y, c = threadIdx.x;
    int n0 = seg * 313;
    int n1 = n0 + 313; if (n1 > N_) n1 = N_;
    const float* p = h + (size_t)t * N_ * H_ + c;
    float s = 0.0f;
    for (int n = n0; n < n1; ++n) s += p[(size_t)n * H_];
    atomicAdd(&z[t * H_ + c], s);
}

// ---------------- head: attention + MLP + LN + pool + linear ----------------
__global__ __launch_bounds__(256) void k_head(
    const float* __restrict__ z,
    const float* __restrict__ Wq, const float* __restrict__ bq,
    const float* __restrict__ Wk, const float* __restrict__ bk,
    const float* __restrict__ Wv, const float* __restrict__ bv,
    const float* __restrict__ Wo, const float* __restrict__ bo,
    const float* __restrict__ g2, const float* __restrict__ beta2,
    const float* __restrict__ Wm1, const float* __restrict__ bm1,
    const float* __restrict__ Wm2, const float* __restrict__ bm2,
    const float* __restrict__ Wl, const float* __restrict__ bl,
    float* __restrict__ out) {
    __shared__ float S0[32 * 128];
    __shared__ float S1[32 * 128];
    __shared__ float S2[32 * 128];
    __shared__ float S3[32 * 128];
    int tid = threadIdx.x;

    for (int i = tid; i < 32 * 128; i += 256) S0[i] = z[i];
    __syncthreads();

    for (int i = tid; i < 32 * 128; i += 256) {
        int t = i >> 7, c = i & 127;
        float aq = bq[c], ak = bk[c], av = bv[c];
        for (int k = 0; k < 128; ++k) {
            float zv = S0[(t << 7) + k];
            aq += zv * Wq[(k << 7) + c];
            ak += zv * Wk[(k << 7) + c];
            av += zv * Wv[(k << 7) + c];
        }
        S1[i] = aq; S2[i] = ak; S3[i] = av;
    }
    __syncthreads();

    {
        int h = tid >> 5, t = tid & 31;
        float sc[32];
        float m = -1e30f;
        for (int s = 0; s < 32; ++s) {
            float d = 0.0f;
#pragma unroll
            for (int k = 0; k < 16; ++k)
                d += S1[(t << 7) + (h << 4) + k] * S2[(s << 7) + (h << 4) + k];
            d *= 0.25f;
            sc[s] = d;
            m = fmaxf(m, d);
        }
        float l = 0.0f;
        for (int s = 0; s < 32; ++s) { sc[s] = __expf(sc[s] - m); l += sc[s]; }
        float inv = 1.0f / l;
        float o[16];
#pragma unroll
        for (int d = 0; d < 16; ++d) o[d] = 0.0f;
        for (int s = 0; s < 32; ++s) {
            float a = sc[s] * inv;
#pragma unroll
            for (int d = 0; d < 16; ++d) o[d] += a * S3[(s << 7) + (h << 4) + d];
        }
#pragma unroll
        for (int d = 0; d < 16; ++d) S0[(t << 7) + (h << 4) + d] = o[d];
    }
    __syncthreads();

    for (int i = tid; i < 32 * 128; i += 256) {
        int t = i >> 7, c = i & 127;
        float a = bo[c];
        for (int k = 0; k < 128; ++k) a += S0[(t << 7) + k] * Wo[(k << 7) + c];
        S1[i] = a;
    }
    __syncthreads();

    for (int ch = 0; ch < 4; ++ch) {
        for (int i = tid; i < 8 * 512; i += 256) {
            int r = i >> 9, j = i & 511;
            int t = ch * 8 + r;
            float a = bm1[j];
            for (int k = 0; k < 128; ++k) a += S1[(t << 7) + k] * Wm1[(k << 9) + j];
            S2[i] = fmaxf(a, 0.0f);
        }
        __syncthreads();
        for (int i = tid; i < 8 * 128; i += 256) {
            int r = i >> 7, c = i & 127;
            int t = ch * 8 + r;
            float a = bm2[c];
            for (int j = 0; j < 512; ++j) a += S2[(r << 9) + j] * Wm2[(j << 7) + c];
            S3[(t << 7) + c] = S1[(t << 7) + c] + a;
        }
        __syncthreads();
    }

    float* pooled = S0;
    float* mu_s = S0 + 128;
    float* rs_s = S0 + 160;
    if (tid < 32) {
        float s = 0.0f, s2 = 0.0f;
        for (int c = 0; c < 128; ++c) {
            float v = S3[(tid << 7) + c];
            s += v; s2 += v * v;
        }
        float mu = s * (1.0f / 128.0f);
        float var = s2 * (1.0f / 128.0f) - mu * mu;
        mu_s[tid] = mu;
        rs_s[tid] = rsqrtf(var + 1e-5f);
    }
    if (tid < 128) pooled[tid] = 0.0f;
    __syncthreads();
    for (int i = tid; i < 32 * 128; i += 256) {
        int t = i >> 7, c = i & 127;
        float v = (S3[i] - mu_s[t]) * rs_s[t] * g2[c] + beta2[c];
        v = fmaxf(v, 0.0f);
        atomicAdd(&pooled[c], v);
    }
    __syncthreads();
    if (tid < C_) {
        float a = bl[tid];
        for (int k = 0; k < 128; ++k) a += pooled[k] * Wl[k * C_ + tid];
        out[tid] = a;
    }
}

extern "C" void kernel_launch(void* const* d_in, const int* in_sizes, int n_in,
                              void* d_out, int out_size, void* d_ws, size_t ws_size,
                              hipStream_t stream) {
    const float* x  = (const float*)d_in[0];
    const int*   ei = (const int*)d_in[1];
    const float* W0 = (const float*)d_in[2];  const float* b0 = (const float*)d_in[3];
    const float* W1 = (const float*)d_in[4];  const float* b1 = (const float*)d_in[5];
    const float* W2 = (const float*)d_in[6];  const float* b2 = (const float*)d_in[7];
    const float* Wq = (const float*)d_in[8];  const float* bq = (const float*)d_in[9];
    const float* Wk = (const float*)d_in[10]; const float* bk = (const float*)d_in[11];
    const float* Wv = (const float*)d_in[12]; const float* bv = (const float*)d_in[13];
    const float* Wo = (const float*)d_in[14]; const float* bo = (const float*)d_in[15];
    const float* g2 = (const float*)d_in[16]; const float* beta2 = (const float*)d_in[17];
    const float* Wm1 = (const float*)d_in[18]; const float* bm1 = (const float*)d_in[19];
    const float* Wm2 = (const float*)d_in[20]; const float* bm2 = (const float*)d_in[21];
    const float* Wl = (const float*)d_in[22]; const float* bl = (const float*)d_in[23];
    float* outp = (float*)d_out;

    const size_t BIG = (size_t)T_ * N_ * H_;  // 20,480,000 floats
    char* ws = (char*)d_ws;
    float*    dinv = (float*)(ws);                       // 160000 f = 640 KB
    int*      ptr  = (int*)(ws + 640000);                // 160000 i = 640 KB
    uint16_t* col  = (uint16_t*)(ws + 1280000);          // 2.56M u16 = 5.12 MB
    float*    P    = (float*)(ws + 6400000);             // BIG
    float*    Q    = P + BIG;                            // BIG
    float*    z    = Q + BIG;                            // 4096 f

    // CSR build + dinv
    hipMemsetAsync(ptr, 0, T_ * N_ * sizeof(int), stream);
    k_count<<<dim3((E_ + 255) / 256, T_), 256, 0, stream>>>(ei, ptr);
    k_scan<<<T_, 256, 0, stream>>>(ptr, dinv);
    k_scatter<<<dim3((E_ + 255) / 256, T_), 256, 0, stream>>>(ei, ptr, col);

    const float* Wl_[3] = {W0, W1, W2};
    const float* bl_[3] = {b0, b1, b2};
    const float* cur = x;
    for (int l = 0; l < 3; ++l) {
        k_gemm<<<dim3(79, T_), 256, 0, stream>>>(cur, Wl_[l], dinv, P);
        k_aggr<<<dim3(N_ / 4, T_), 256, 0, stream>>>(ptr, col, P, dinv, bl_[l], Q);
        cur = Q;
    }

    k_zinit<<<(T_ * H_ + 255) / 256, 256, 0, stream>>>(z);
    k_reduce<<<dim3(T_, 16), 128, 0, stream>>>(Q, z);

    k_head<<<1, 256, 0, stream>>>(z, Wq, bq, Wk, bk, Wv, bv, Wo, bo,
                                  g2, beta2, Wm1, bm1, Wm2, bm2, Wl, bl, outp);
}

// Round 3
// 1140.204 us; speedup vs baseline: 12.1723x; 1.4805x over previous
//
#include <hip/hip_runtime.h>
#include <cstdint>

#define T_ 32
#define N_ 5000
#define E_ 80000
#define H_ 128
#define HD_ 512
#define C_ 10

// ---------------- CSR build ----------------
__global__ __launch_bounds__(256) void k_count(const int* __restrict__ ei, int* __restrict__ ptr) {
    int e = blockIdx.x * 256 + threadIdx.x;
    int t = blockIdx.y;
    if (e < E_) {
        int d = ei[(size_t)t * 2 * E_ + E_ + e];
        atomicAdd(&ptr[t * N_ + d], 1);
    }
}

__global__ __launch_bounds__(256) void k_scan(int* __restrict__ ptr, float* __restrict__ dinv) {
    int t = blockIdx.x, tid = threadIdx.x;
    __shared__ int part[256];
    int base = t * N_;
    int vals[20];
    int sum = 0;
#pragma unroll
    for (int j = 0; j < 20; ++j) {
        int i = tid * 20 + j;
        int c = 0;
        if (i < N_) {
            c = ptr[base + i];
            dinv[base + i] = rsqrtf((float)(c + 1));
        }
        vals[j] = sum;
        sum += c;
    }
    part[tid] = sum;
    __syncthreads();
    for (int off = 1; off < 256; off <<= 1) {
        int v = (tid >= off) ? part[tid - off] : 0;
        __syncthreads();
        part[tid] += v;
        __syncthreads();
    }
    int prev = (tid > 0) ? part[tid - 1] : 0;
#pragma unroll
    for (int j = 0; j < 20; ++j) {
        int i = tid * 20 + j;
        if (i < N_) ptr[base + i] = prev + vals[j];
    }
}

__global__ __launch_bounds__(256) void k_scatter(const int* __restrict__ ei,
                                                 int* __restrict__ ptr,
                                                 uint16_t* __restrict__ col) {
    int e = blockIdx.x * 256 + threadIdx.x;
    int t = blockIdx.y;
    if (e < E_) {
        int s = ei[(size_t)t * 2 * E_ + e];
        int d = ei[(size_t)t * 2 * E_ + E_ + e];
        int pos = atomicAdd(&ptr[t * N_ + d], 1);
        col[(size_t)t * E_ + pos] = (uint16_t)s;
    }
}

// ---------------- GEMM: g[t][r][c] = dinv[t][r] * sum_k in[t][r][k]*W[k][c] ----------------
__global__ __launch_bounds__(256) void k_gemm(const float* __restrict__ in,
                                              const float* __restrict__ W,
                                              const float* __restrict__ dinv,
                                              float* __restrict__ g) {
    __shared__ float Ws[32 * 128];
    __shared__ float As[32 * 68];
    int t = blockIdx.y;
    int r0 = blockIdx.x * 64;
    int tid = threadIdx.x;
    int nrows = N_ - r0; if (nrows > 64) nrows = 64;
    const float* Ain = in + ((size_t)t * N_ + r0) * H_;
    int tr = tid >> 5, tc = tid & 31;
    int rr = tr * 8, cc = tc * 4;
    float acc[8][4];
#pragma unroll
    for (int i = 0; i < 8; ++i)
#pragma unroll
        for (int j = 0; j < 4; ++j) acc[i][j] = 0.0f;

    for (int kb = 0; kb < 4; ++kb) {
        for (int i = tid * 4; i < 32 * 128; i += 1024)
            *(float4*)&Ws[i] = *(const float4*)&W[kb * 4096 + i];
        for (int i = tid; i < 512; i += 256) {
            int r = i >> 3, kq = (i & 7) * 4;
            float4 v = make_float4(0.f, 0.f, 0.f, 0.f);
            if (r < nrows) v = *(const float4*)&Ain[r * H_ + kb * 32 + kq];
            As[(kq + 0) * 68 + r] = v.x;
            As[(kq + 1) * 68 + r] = v.y;
            As[(kq + 2) * 68 + r] = v.z;
            As[(kq + 3) * 68 + r] = v.w;
        }
        __syncthreads();
#pragma unroll
        for (int k = 0; k < 32; ++k) {
            float4 a0 = *(const float4*)&As[k * 68 + rr];
            float4 a1 = *(const float4*)&As[k * 68 + rr + 4];
            float4 w  = *(const float4*)&Ws[k * 128 + cc];
            float av[8] = {a0.x, a0.y, a0.z, a0.w, a1.x, a1.y, a1.z, a1.w};
            float wv[4] = {w.x, w.y, w.z, w.w};
#pragma unroll
            for (int i = 0; i < 8; ++i)
#pragma unroll
                for (int j = 0; j < 4; ++j) acc[i][j] += av[i] * wv[j];
        }
        __syncthreads();
    }
#pragma unroll
    for (int i = 0; i < 8; ++i) {
        int r = rr + i;
        if (r < nrows) {
            float d = dinv[t * N_ + r0 + r];
            float4 o = make_float4(acc[i][0] * d, acc[i][1] * d, acc[i][2] * d, acc[i][3] * d);
            *(float4*)&g[((size_t)t * N_ + r0 + r) * H_ + cc] = o;
        }
    }
}

// ---------------- CSR gather, float4 x 2-edge halves ----------------
__global__ __launch_bounds__(256) void k_aggr(const int* __restrict__ ptr,
                                              const uint16_t* __restrict__ col,
                                              const float* __restrict__ g,
                                              const float* __restrict__ dinv,
                                              const float* __restrict__ b,
                                              float* __restrict__ out) {
    int t = blockIdx.y;
    int n = blockIdx.x * 4 + (threadIdx.x >> 6);
    int lane = threadIdx.x & 63;
    int half = lane >> 5;
    int c = (lane & 31) * 4;
    int base = t * N_;
    int begin = (n == 0) ? 0 : ptr[base + n - 1];
    int end = ptr[base + n];
    const float* gg = g + (size_t)base * H_;
    const uint16_t* cl = col + (size_t)t * E_;
    float4 acc = make_float4(0.f, 0.f, 0.f, 0.f);
    if (half == 0) acc = *(const float4*)&gg[(size_t)n * H_ + c];  // self-loop
    for (int i = begin + half; i < end; i += 2) {
        int s = cl[i];
        float4 v = *(const float4*)&gg[(size_t)s * H_ + c];
        acc.x += v.x; acc.y += v.y; acc.z += v.z; acc.w += v.w;
    }
    // combine the two halves (features identical, edges disjoint)
    acc.x += __shfl(acc.x, lane ^ 32, 64);
    acc.y += __shfl(acc.y, lane ^ 32, 64);
    acc.z += __shfl(acc.z, lane ^ 32, 64);
    acc.w += __shfl(acc.w, lane ^ 32, 64);
    if (half == 0) {
        float d = dinv[base + n];
        float4 o;
        o.x = tanhf(d * acc.x + b[c + 0]);
        o.y = tanhf(d * acc.y + b[c + 1]);
        o.z = tanhf(d * acc.z + b[c + 2]);
        o.w = tanhf(d * acc.w + b[c + 3]);
        *(float4*)&out[((size_t)base + n) * H_ + c] = o;
    }
}

// ---------------- node-sum: z[t][c] = sum_n h[t][n][c] ----------------
__global__ __launch_bounds__(256) void k_zinit(float* z) {
    int i = blockIdx.x * 256 + threadIdx.x;
    if (i < T_ * H_) z[i] = 0.0f;
}

__global__ __launch_bounds__(256) void k_reduce(const float* __restrict__ h, float* __restrict__ z) {
    int t = blockIdx.x, seg = blockIdx.y;
    int tid = threadIdx.x;
    int rg = tid >> 5;             // 8 row groups
    int c = (tid & 31) * 4;
    const float* p = h + (size_t)t * N_ * H_;
    float4 acc = make_float4(0.f, 0.f, 0.f, 0.f);
    int n0 = seg * 500;
    for (int n = n0 + rg; n < n0 + 500; n += 8) {
        float4 v = *(const float4*)&p[(size_t)n * H_ + c];
        acc.x += v.x; acc.y += v.y; acc.z += v.z; acc.w += v.w;
    }
    __shared__ float4 part[256];
    part[tid] = acc;
    __syncthreads();
    if (rg == 0) {
        float4 s = part[tid];
#pragma unroll
        for (int j = 1; j < 8; ++j) {
            float4 v = part[(j << 5) + tid];
            s.x += v.x; s.y += v.y; s.z += v.z; s.w += v.w;
        }
        atomicAdd(&z[t * H_ + c + 0], s.x);
        atomicAdd(&z[t * H_ + c + 1], s.y);
        atomicAdd(&z[t * H_ + c + 2], s.z);
        atomicAdd(&z[t * H_ + c + 3], s.w);
    }
}

// ---------------- head stage 1: q,k,v = z @ W + b (one block per t) ----------------
__global__ __launch_bounds__(128) void k_qkv(const float* __restrict__ z,
                                             const float* __restrict__ Wq, const float* __restrict__ bq,
                                             const float* __restrict__ Wk, const float* __restrict__ bk,
                                             const float* __restrict__ Wv, const float* __restrict__ bv,
                                             float* __restrict__ q, float* __restrict__ k,
                                             float* __restrict__ v) {
    int t = blockIdx.x, c = threadIdx.x;
    __shared__ float zs[128];
    zs[c] = z[t * 128 + c];
    __syncthreads();
    float aq = bq[c], ak = bk[c], av = bv[c];
    for (int kk = 0; kk < 128; ++kk) {
        float zv = zs[kk];
        aq += zv * Wq[(kk << 7) + c];
        ak += zv * Wk[(kk << 7) + c];
        av += zv * Wv[(kk << 7) + c];
    }
    q[t * 128 + c] = aq;
    k[t * 128 + c] = ak;
    v[t * 128 + c] = av;
}

// ---------------- head stage 2: attention + Wo + MLP + LN + relu (one block per t) ----------------
__global__ __launch_bounds__(256) void k_attnmid(
    const float* __restrict__ q, const float* __restrict__ k, const float* __restrict__ v,
    const float* __restrict__ Wo, const float* __restrict__ bo,
    const float* __restrict__ g2, const float* __restrict__ beta2,
    const float* __restrict__ Wm1, const float* __restrict__ bm1,
    const float* __restrict__ Wm2, const float* __restrict__ bm2,
    float* __restrict__ xr) {
    int t = blockIdx.x, tid = threadIdx.x;
    __shared__ float Ks[32 * 128], Vs[32 * 128];
    __shared__ float qs[128], sc[8 * 32], xa[128], hid[512], ys[128];
    __shared__ float redA[128], redB[128];

    for (int i = tid; i < 32 * 128; i += 256) { Ks[i] = k[i]; Vs[i] = v[i]; }
    if (tid < 128) qs[tid] = q[t * 128 + tid];
    __syncthreads();

    // scores: tid = h*32 + s
    {
        int h = tid >> 5, s = tid & 31;
        float d = 0.0f;
#pragma unroll
        for (int kk = 0; kk < 16; ++kk)
            d += qs[(h << 4) + kk] * Ks[(s << 7) + (h << 4) + kk];
        sc[tid] = d * 0.25f;
    }
    __syncthreads();
    // softmax per head (8 threads)
    if (tid < 8) {
        float m = -1e30f;
        for (int s = 0; s < 32; ++s) m = fmaxf(m, sc[(tid << 5) + s]);
        float l = 0.0f;
        for (int s = 0; s < 32; ++s) { float e = __expf(sc[(tid << 5) + s] - m); sc[(tid << 5) + s] = e; l += e; }
        float inv = 1.0f / l;
        for (int s = 0; s < 32; ++s) sc[(tid << 5) + s] *= inv;
    }
    __syncthreads();
    // o[c] = sum_s attn[h][s] * V[s][c]  -> qs (reuse)
    if (tid < 128) {
        int h = tid >> 4;
        float o = 0.0f;
        for (int s = 0; s < 32; ++s) o += sc[(h << 5) + s] * Vs[(s << 7) + tid];
        qs[tid] = o;
    }
    __syncthreads();
    // xa = o @ Wo + bo
    if (tid < 128) {
        float a = bo[tid];
        for (int kk = 0; kk < 128; ++kk) a += qs[kk] * Wo[(kk << 7) + tid];
        xa[tid] = a;
    }
    __syncthreads();
    // hid = relu(xa @ Wm1 + bm1)  (512 outputs, 2 per thread)
    for (int j = tid; j < 512; j += 256) {
        float a = bm1[j];
        for (int kk = 0; kk < 128; ++kk) a += xa[kk] * Wm1[(kk << 9) + j];
        hid[j] = fmaxf(a, 0.0f);
    }
    __syncthreads();
    // y = xa + hid @ Wm2 + bm2
    if (tid < 128) {
        float a = bm2[tid];
        for (int j = 0; j < 512; ++j) a += hid[j] * Wm2[(j << 7) + tid];
        ys[tid] = xa[tid] + a;
    }
    __syncthreads();
    // LayerNorm over 128, then relu, store
    if (tid < 128) { redA[tid] = ys[tid]; redB[tid] = ys[tid] * ys[tid]; }
    __syncthreads();
    for (int off = 64; off > 0; off >>= 1) {
        if (tid < off) { redA[tid] += redA[tid + off]; redB[tid] += redB[tid + off]; }
        __syncthreads();
    }
    float mu = redA[0] * (1.0f / 128.0f);
    float var = redB[0] * (1.0f / 128.0f) - mu * mu;
    float rs = rsqrtf(var + 1e-5f);
    if (tid < 128) {
        float yv = (ys[tid] - mu) * rs * g2[tid] + beta2[tid];
        xr[t * 128 + tid] = fmaxf(yv, 0.0f);
    }
}

// ---------------- head stage 3: pool + final linear ----------------
__global__ __launch_bounds__(128) void k_final(const float* __restrict__ xr,
                                               const float* __restrict__ Wl,
                                               const float* __restrict__ bl,
                                               float* __restrict__ out) {
    int tid = threadIdx.x;
    __shared__ float pooled[128];
    float s = 0.0f;
    for (int t = 0; t < 32; ++t) s += xr[t * 128 + tid];
    pooled[tid] = s;
    __syncthreads();
    if (tid < C_) {
        float a = bl[tid];
        for (int kk = 0; kk < 128; ++kk) a += pooled[kk] * Wl[kk * C_ + tid];
        out[tid] = a;
    }
}

extern "C" void kernel_launch(void* const* d_in, const int* in_sizes, int n_in,
                              void* d_out, int out_size, void* d_ws, size_t ws_size,
                              hipStream_t stream) {
    const float* x  = (const float*)d_in[0];
    const int*   ei = (const int*)d_in[1];
    const float* W0 = (const float*)d_in[2];  const float* b0 = (const float*)d_in[3];
    const float* W1 = (const float*)d_in[4];  const float* b1 = (const float*)d_in[5];
    const float* W2 = (const float*)d_in[6];  const float* b2 = (const float*)d_in[7];
    const float* Wq = (const float*)d_in[8];  const float* bq = (const float*)d_in[9];
    const float* Wk = (const float*)d_in[10]; const float* bk = (const float*)d_in[11];
    const float* Wv = (const float*)d_in[12]; const float* bv = (const float*)d_in[13];
    const float* Wo = (const float*)d_in[14]; const float* bo = (const float*)d_in[15];
    const float* g2 = (const float*)d_in[16]; const float* beta2 = (const float*)d_in[17];
    const float* Wm1 = (const float*)d_in[18]; const float* bm1 = (const float*)d_in[19];
    const float* Wm2 = (const float*)d_in[20]; const float* bm2 = (const float*)d_in[21];
    const float* Wl = (const float*)d_in[22]; const float* bl = (const float*)d_in[23];
    float* outp = (float*)d_out;

    const size_t BIG = (size_t)T_ * N_ * H_;
    char* ws = (char*)d_ws;
    float*    dinv = (float*)(ws);                  // 640 KB
    int*      ptr  = (int*)(ws + 640000);           // 640 KB
    uint16_t* col  = (uint16_t*)(ws + 1280000);     // 5.12 MB
    float*    P    = (float*)(ws + 6400000);        // BIG
    float*    Q    = P + BIG;                       // BIG
    float*    z    = Q + BIG;                       // 4096 f
    float*    zq   = z + 4096;
    float*    zk   = zq + 4096;
    float*    zv   = zk + 4096;
    float*    xr   = zv + 4096;

    hipMemsetAsync(ptr, 0, T_ * N_ * sizeof(int), stream);
    k_count<<<dim3((E_ + 255) / 256, T_), 256, 0, stream>>>(ei, ptr);
    k_scan<<<T_, 256, 0, stream>>>(ptr, dinv);
    k_scatter<<<dim3((E_ + 255) / 256, T_), 256, 0, stream>>>(ei, ptr, col);

    const float* Wl_[3] = {W0, W1, W2};
    const float* bl_[3] = {b0, b1, b2};
    const float* cur = x;
    for (int l = 0; l < 3; ++l) {
        k_gemm<<<dim3(79, T_), 256, 0, stream>>>(cur, Wl_[l], dinv, P);
        k_aggr<<<dim3(N_ / 4, T_), 256, 0, stream>>>(ptr, col, P, dinv, bl_[l], Q);
        cur = Q;
    }

    k_zinit<<<(T_ * H_ + 255) / 256, 256, 0, stream>>>(z);
    k_reduce<<<dim3(T_, 10), 256, 0, stream>>>(Q, z);

    k_qkv<<<T_, 128, 0, stream>>>(z, Wq, bq, Wk, bk, Wv, bv, zq, zk, zv);
    k_attnmid<<<T_, 256, 0, stream>>>(zq, zk, zv, Wo, bo, g2, beta2,
                                      Wm1, bm1, Wm2, bm2, xr);
    k_final<<<1, 128, 0, stream>>>(xr, Wl, bl, outp);
}

// Round 4
// 956.100 us; speedup vs baseline: 14.5162x; 1.1926x over previous
//
#include <hip/hip_runtime.h>
#include <cstdint>

#define T_ 32
#define N_ 5000
#define E_ 80000
#define H_ 128
#define HD_ 512
#define C_ 10

typedef _Float16 f16;
typedef f16 f16x8 __attribute__((ext_vector_type(8)));
typedef f16 f16x4 __attribute__((ext_vector_type(4)));
typedef float f32x4 __attribute__((ext_vector_type(4)));

#define LDA 136  // padded LDS leading dim in f16 (stride 272 B -> 2-way bank alias, free)

// ---------------- CSR build ----------------
__global__ __launch_bounds__(256) void k_count(const int* __restrict__ ei, int* __restrict__ ptr) {
    int e = blockIdx.x * 256 + threadIdx.x;
    int t = blockIdx.y;
    if (e < E_) {
        int d = ei[(size_t)t * 2 * E_ + E_ + e];
        atomicAdd(&ptr[t * N_ + d], 1);
    }
}

__global__ __launch_bounds__(256) void k_scan(int* __restrict__ ptr, float* __restrict__ dinv) {
    int t = blockIdx.x, tid = threadIdx.x;
    __shared__ int part[256];
    int base = t * N_;
    int vals[20];
    int sum = 0;
#pragma unroll
    for (int j = 0; j < 20; ++j) {
        int i = tid * 20 + j;
        int c = 0;
        if (i < N_) {
            c = ptr[base + i];
            dinv[base + i] = rsqrtf((float)(c + 1));
        }
        vals[j] = sum;
        sum += c;
    }
    part[tid] = sum;
    __syncthreads();
    for (int off = 1; off < 256; off <<= 1) {
        int v = (tid >= off) ? part[tid - off] : 0;
        __syncthreads();
        part[tid] += v;
        __syncthreads();
    }
    int prev = (tid > 0) ? part[tid - 1] : 0;
#pragma unroll
    for (int j = 0; j < 20; ++j) {
        int i = tid * 20 + j;
        if (i < N_) ptr[base + i] = prev + vals[j];
    }
}

__global__ __launch_bounds__(256) void k_scatter(const int* __restrict__ ei,
                                                 int* __restrict__ ptr,
                                                 uint16_t* __restrict__ col) {
    int e = blockIdx.x * 256 + threadIdx.x;
    int t = blockIdx.y;
    if (e < E_) {
        int s = ei[(size_t)t * 2 * E_ + e];
        int d = ei[(size_t)t * 2 * E_ + E_ + e];
        int pos = atomicAdd(&ptr[t * N_ + d], 1);
        col[(size_t)t * E_ + pos] = (uint16_t)s;
    }
}

// ---------------- weight prep: Wt[l][c][k] = (f16)W_l[k][c] ----------------
__global__ __launch_bounds__(256) void k_wprep(const float* __restrict__ W0,
                                               const float* __restrict__ W1,
                                               const float* __restrict__ W2,
                                               f16* __restrict__ Wt) {
    const float* W = (blockIdx.x == 0) ? W0 : (blockIdx.x == 1) ? W1 : W2;
    f16* dst = Wt + blockIdx.x * 16384;
    for (int idx = threadIdx.x; idx < 16384; idx += 256) {
        int c = idx >> 7, k = idx & 127;
        dst[idx] = (f16)W[k * 128 + c];
    }
}

// ---------------- MFMA GEMM: g[t][r][c] = dinv[t][r] * sum_k in[t][r][k]*W[k][c] (f16 out) ----------------
// block = 256 thr = 4 waves, tile 64 rows x 128 cols, K=128. 1-D grid, t = b&31 (XCD affinity).
template <bool F32IN>
__global__ __launch_bounds__(256) void k_gemm(const void* __restrict__ in_,
                                              const f16* __restrict__ Wt,  // [c][k]
                                              const float* __restrict__ dinv,
                                              f16* __restrict__ g) {
    __shared__ f16 Ws[128 * LDA];  // [c][k] padded
    __shared__ f16 As[64 * LDA];   // [r][k] padded; reused for epilogue
    int b = blockIdx.x;
    int t = b & 31;
    int r0 = (b >> 5) * 64;
    int tid = threadIdx.x;

    // stage Wt -> Ws (each thread: one half-row = 64 f16)
    {
        int c = tid >> 1, hf = tid & 1;
        const f16* src = Wt + c * 128 + hf * 64;
        f16* dst = Ws + c * LDA + hf * 64;
#pragma unroll
        for (int j = 0; j < 8; ++j) *(f16x8*)&dst[j * 8] = *(const f16x8*)&src[j * 8];
    }
    // stage A -> As (each thread: one row-quarter = 32 elems)
    {
        int r = tid >> 2, kq = (tid & 3) * 32;
        bool valid = (r0 + r) < N_;
        f16* dst = As + r * LDA + kq;
        if (F32IN) {
            const float* src = (const float*)in_ + ((size_t)(t * N_ + r0 + r)) * H_ + kq;
#pragma unroll
            for (int j = 0; j < 8; ++j) {
                float4 v = valid ? *(const float4*)&src[j * 4] : make_float4(0.f, 0.f, 0.f, 0.f);
                dst[j * 4 + 0] = (f16)v.x;
                dst[j * 4 + 1] = (f16)v.y;
                dst[j * 4 + 2] = (f16)v.z;
                dst[j * 4 + 3] = (f16)v.w;
            }
        } else {
            const f16* src = (const f16*)in_ + ((size_t)(t * N_ + r0 + r)) * H_ + kq;
#pragma unroll
            for (int j = 0; j < 4; ++j) {
                f16x8 v = {};
                if (valid) v = *(const f16x8*)&src[j * 8];
                *(f16x8*)&dst[j * 8] = v;
            }
        }
    }
    __syncthreads();

    int w = tid >> 6, lane = tid & 63;
    int m = lane & 15, q = lane >> 4;
    int rw = w * 16;
    f32x4 acc[8];
#pragma unroll
    for (int n = 0; n < 8; ++n) acc[n] = (f32x4){0.f, 0.f, 0.f, 0.f};

#pragma unroll
    for (int kb = 0; kb < 4; ++kb) {
        f16x8 aF = *(const f16x8*)&As[(rw + m) * LDA + kb * 32 + q * 8];
#pragma unroll
        for (int n = 0; n < 8; ++n) {
            f16x8 bF = *(const f16x8*)&Ws[(n * 16 + m) * LDA + kb * 32 + q * 8];
            acc[n] = __builtin_amdgcn_mfma_f32_16x16x32_f16(aF, bF, acc[n], 0, 0, 0);
        }
    }
    __syncthreads();  // done reading As; reuse for output staging

    // acc -> As[r][c] (scaled by dinv), then coalesced f16 writes
#pragma unroll
    for (int i = 0; i < 4; ++i) {
        int rr = rw + q * 4 + i;
        int gr = r0 + rr;
        float d = dinv[t * N_ + (gr < N_ ? gr : N_ - 1)];
#pragma unroll
        for (int n = 0; n < 8; ++n)
            As[rr * LDA + n * 16 + m] = (f16)(acc[n][i] * d);
    }
    __syncthreads();
    {
        int r = tid >> 2, kq = (tid & 3) * 32;
        if (r0 + r < N_) {
            f16* dst = g + ((size_t)(t * N_ + r0 + r)) * H_ + kq;
            const f16* src = As + r * LDA + kq;
#pragma unroll
            for (int j = 0; j < 4; ++j) *(f16x8*)&dst[j * 8] = *(const f16x8*)&src[j * 8];
        }
    }
}

// ---------------- CSR gather + epilogue (f16 in/out, fp32 accumulate) ----------------
// 1-D grid, t = b&31; wave per node; quarter-wave (16 lanes x f16x8) per edge, 4 edges in flight
__global__ __launch_bounds__(256) void k_aggr(const int* __restrict__ ptr,
                                              const uint16_t* __restrict__ col,
                                              const f16* __restrict__ g,
                                              const float* __restrict__ dinv,
                                              const float* __restrict__ b,
                                              f16* __restrict__ out) {
    int blk = blockIdx.x;
    int t = blk & 31;
    int n = (blk >> 5) * 4 + (threadIdx.x >> 6);
    int lane = threadIdx.x & 63;
    int q = lane >> 4, m = lane & 15;
    int base = t * N_;
    int begin = (n == 0) ? 0 : ptr[base + n - 1];
    int end = ptr[base + n];
    const f16* gg = g + (size_t)base * H_;
    const uint16_t* cl = col + (size_t)t * E_;
    float acc[8];
    if (q == 0) {
        f16x8 v = *(const f16x8*)&gg[(size_t)n * H_ + m * 8];  // self-loop
#pragma unroll
        for (int j = 0; j < 8; ++j) acc[j] = (float)v[j];
    } else {
#pragma unroll
        for (int j = 0; j < 8; ++j) acc[j] = 0.0f;
    }
    for (int i = begin + q; i < end; i += 4) {
        int s = cl[i];
        f16x8 v = *(const f16x8*)&gg[(size_t)s * H_ + m * 8];
#pragma unroll
        for (int j = 0; j < 8; ++j) acc[j] += (float)v[j];
    }
#pragma unroll
    for (int j = 0; j < 8; ++j) acc[j] += __shfl(acc[j], lane ^ 16, 64);
#pragma unroll
    for (int j = 0; j < 8; ++j) acc[j] += __shfl(acc[j], lane ^ 32, 64);
    if (q == 0) {
        float d = dinv[base + n];
        f16x8 o;
#pragma unroll
        for (int j = 0; j < 8; ++j) o[j] = (f16)tanhf(d * acc[j] + b[m * 8 + j]);
        *(f16x8*)&out[((size_t)base + n) * H_ + m * 8] = o;
    }
}

// ---------------- node-sum: z[t][c] = sum_n h[t][n][c] ----------------
__global__ __launch_bounds__(256) void k_zinit(float* z) {
    int i = blockIdx.x * 256 + threadIdx.x;
    if (i < T_ * H_) z[i] = 0.0f;
}

__global__ __launch_bounds__(256) void k_reduce(const f16* __restrict__ h, float* __restrict__ z) {
    int t = blockIdx.x, seg = blockIdx.y;
    int tid = threadIdx.x;
    int rg = tid >> 5;
    int c = (tid & 31) * 4;
    const f16* p = h + (size_t)t * N_ * H_;
    float4 acc = make_float4(0.f, 0.f, 0.f, 0.f);
    int n0 = seg * 500;
    for (int n = n0 + rg; n < n0 + 500; n += 8) {
        f16x4 v = *(const f16x4*)&p[(size_t)n * H_ + c];
        acc.x += (float)v[0]; acc.y += (float)v[1]; acc.z += (float)v[2]; acc.w += (float)v[3];
    }
    __shared__ float4 part[256];
    part[tid] = acc;
    __syncthreads();
    if (rg == 0) {
        float4 s = part[tid];
#pragma unroll
        for (int j = 1; j < 8; ++j) {
            float4 v = part[(j << 5) + tid];
            s.x += v.x; s.y += v.y; s.z += v.z; s.w += v.w;
        }
        atomicAdd(&z[t * H_ + c + 0], s.x);
        atomicAdd(&z[t * H_ + c + 1], s.y);
        atomicAdd(&z[t * H_ + c + 2], s.z);
        atomicAdd(&z[t * H_ + c + 3], s.w);
    }
}

// ---------------- head stage 1: q,k,v ----------------
__global__ __launch_bounds__(128) void k_qkv(const float* __restrict__ z,
                                             const float* __restrict__ Wq, const float* __restrict__ bq,
                                             const float* __restrict__ Wk, const float* __restrict__ bk,
                                             const float* __restrict__ Wv, const float* __restrict__ bv,
                                             float* __restrict__ q, float* __restrict__ k,
                                             float* __restrict__ v) {
    int t = blockIdx.x, c = threadIdx.x;
    __shared__ float zs[128];
    zs[c] = z[t * 128 + c];
    __syncthreads();
    float aq = bq[c], ak = bk[c], av = bv[c];
    for (int kk = 0; kk < 128; ++kk) {
        float zv = zs[kk];
        aq += zv * Wq[(kk << 7) + c];
        ak += zv * Wk[(kk << 7) + c];
        av += zv * Wv[(kk << 7) + c];
    }
    q[t * 128 + c] = aq;
    k[t * 128 + c] = ak;
    v[t * 128 + c] = av;
}

// ---------------- head stage 2 ----------------
__global__ __launch_bounds__(256) void k_attnmid(
    const float* __restrict__ q, const float* __restrict__ k, const float* __restrict__ v,
    const float* __restrict__ Wo, const float* __restrict__ bo,
    const float* __restrict__ g2, const float* __restrict__ beta2,
    const float* __restrict__ Wm1, const float* __restrict__ bm1,
    const float* __restrict__ Wm2, const float* __restrict__ bm2,
    float* __restrict__ xr) {
    int t = blockIdx.x, tid = threadIdx.x;
    __shared__ float Ks[32 * 128], Vs[32 * 128];
    __shared__ float qs[128], sc[8 * 32], xa[128], hid[512], ys[128];
    __shared__ float redA[128], redB[128];

    for (int i = tid; i < 32 * 128; i += 256) { Ks[i] = k[i]; Vs[i] = v[i]; }
    if (tid < 128) qs[tid] = q[t * 128 + tid];
    __syncthreads();

    {
        int h = tid >> 5, s = tid & 31;
        float d = 0.0f;
#pragma unroll
        for (int kk = 0; kk < 16; ++kk)
            d += qs[(h << 4) + kk] * Ks[(s << 7) + (h << 4) + kk];
        sc[tid] = d * 0.25f;
    }
    __syncthreads();
    if (tid < 8) {
        float m = -1e30f;
        for (int s = 0; s < 32; ++s) m = fmaxf(m, sc[(tid << 5) + s]);
        float l = 0.0f;
        for (int s = 0; s < 32; ++s) { float e = __expf(sc[(tid << 5) + s] - m); sc[(tid << 5) + s] = e; l += e; }
        float inv = 1.0f / l;
        for (int s = 0; s < 32; ++s) sc[(tid << 5) + s] *= inv;
    }
    __syncthreads();
    if (tid < 128) {
        int h = tid >> 4;
        float o = 0.0f;
        for (int s = 0; s < 32; ++s) o += sc[(h << 5) + s] * Vs[(s << 7) + tid];
        qs[tid] = o;
    }
    __syncthreads();
    if (tid < 128) {
        float a = bo[tid];
        for (int kk = 0; kk < 128; ++kk) a += qs[kk] * Wo[(kk << 7) + tid];
        xa[tid] = a;
    }
    __syncthreads();
    for (int j = tid; j < 512; j += 256) {
        float a = bm1[j];
        for (int kk = 0; kk < 128; ++kk) a += xa[kk] * Wm1[(kk << 9) + j];
        hid[j] = fmaxf(a, 0.0f);
    }
    __syncthreads();
    if (tid < 128) {
        float a = bm2[tid];
        for (int j = 0; j < 512; ++j) a += hid[j] * Wm2[(j << 7) + tid];
        ys[tid] = xa[tid] + a;
    }
    __syncthreads();
    if (tid < 128) { redA[tid] = ys[tid]; redB[tid] = ys[tid] * ys[tid]; }
    __syncthreads();
    for (int off = 64; off > 0; off >>= 1) {
        if (tid < off) { redA[tid] += redA[tid + off]; redB[tid] += redB[tid + off]; }
        __syncthreads();
    }
    float mu = redA[0] * (1.0f / 128.0f);
    float var = redB[0] * (1.0f / 128.0f) - mu * mu;
    float rs = rsqrtf(var + 1e-5f);
    if (tid < 128) {
        float yv = (ys[tid] - mu) * rs * g2[tid] + beta2[tid];
        xr[t * 128 + tid] = fmaxf(yv, 0.0f);
    }
}

// ---------------- head stage 3 ----------------
__global__ __launch_bounds__(128) void k_final(const float* __restrict__ xr,
                                               const float* __restrict__ Wl,
                                               const float* __restrict__ bl,
                                               float* __restrict__ out) {
    int tid = threadIdx.x;
    __shared__ float pooled[128];
    float s = 0.0f;
    for (int t = 0; t < 32; ++t) s += xr[t * 128 + tid];
    pooled[tid] = s;
    __syncthreads();
    if (tid < C_) {
        float a = bl[tid];
        for (int kk = 0; kk < 128; ++kk) a += pooled[kk] * Wl[kk * C_ + tid];
        out[tid] = a;
    }
}

extern "C" void kernel_launch(void* const* d_in, const int* in_sizes, int n_in,
                              void* d_out, int out_size, void* d_ws, size_t ws_size,
                              hipStream_t stream) {
    const float* x  = (const float*)d_in[0];
    const int*   ei = (const int*)d_in[1];
    const float* W0 = (const float*)d_in[2];  const float* b0 = (const float*)d_in[3];
    const float* W1 = (const float*)d_in[4];  const float* b1 = (const float*)d_in[5];
    const float* W2 = (const float*)d_in[6];  const float* b2 = (const float*)d_in[7];
    const float* Wq = (const float*)d_in[8];  const float* bq = (const float*)d_in[9];
    const float* Wk = (const float*)d_in[10]; const float* bk = (const float*)d_in[11];
    const float* Wv = (const float*)d_in[12]; const float* bv = (const float*)d_in[13];
    const float* Wo = (const float*)d_in[14]; const float* bo = (const float*)d_in[15];
    const float* g2 = (const float*)d_in[16]; const float* beta2 = (const float*)d_in[17];
    const float* Wm1 = (const float*)d_in[18]; const float* bm1 = (const float*)d_in[19];
    const float* Wm2 = (const float*)d_in[20]; const float* bm2 = (const float*)d_in[21];
    const float* Wl = (const float*)d_in[22]; const float* bl = (const float*)d_in[23];
    float* outp = (float*)d_out;

    const size_t BIG = (size_t)T_ * N_ * H_;  // 20.48M elements
    char* ws = (char*)d_ws;
    float*    dinv = (float*)(ws);                  // 640 KB
    int*      ptr  = (int*)(ws + 640000);           // 640 KB
    uint16_t* col  = (uint16_t*)(ws + 1280000);     // 5.12 MB
    f16*      Wt   = (f16*)(ws + 6400000);          // 96 KB (3 layers, [c][k])
    f16*      P16  = (f16*)(ws + 6498304);          // 41 MB
    f16*      Q16  = P16 + BIG;                     // 41 MB
    float*    z    = (float*)(Q16 + BIG);
    float*    zq   = z + 4096;
    float*    zk   = zq + 4096;
    float*    zv   = zk + 4096;
    float*    xr   = zv + 4096;

    hipMemsetAsync(ptr, 0, T_ * N_ * sizeof(int), stream);
    k_wprep<<<3, 256, 0, stream>>>(W0, W1, W2, Wt);
    k_count<<<dim3((E_ + 255) / 256, T_), 256, 0, stream>>>(ei, ptr);
    k_scan<<<T_, 256, 0, stream>>>(ptr, dinv);
    k_scatter<<<dim3((E_ + 255) / 256, T_), 256, 0, stream>>>(ei, ptr, col);

    const float* bl_[3] = {b0, b1, b2};
    // layer 0 (fp32 input)
    k_gemm<true><<<79 * 32, 256, 0, stream>>>(x, Wt, dinv, P16);
    k_aggr<<<(N_ / 4) * 32, 256, 0, stream>>>(ptr, col, P16, dinv, bl_[0], Q16);
    // layer 1
    k_gemm<false><<<79 * 32, 256, 0, stream>>>(Q16, Wt + 16384, dinv, P16);
    k_aggr<<<(N_ / 4) * 32, 256, 0, stream>>>(ptr, col, P16, dinv, bl_[1], Q16);
    // layer 2
    k_gemm<false><<<79 * 32, 256, 0, stream>>>(Q16, Wt + 32768, dinv, P16);
    k_aggr<<<(N_ / 4) * 32, 256, 0, stream>>>(ptr, col, P16, dinv, bl_[2], Q16);

    k_zinit<<<(T_ * H_ + 255) / 256, 256, 0, stream>>>(z);
    k_reduce<<<dim3(T_, 10), 256, 0, stream>>>(Q16, z);

    k_qkv<<<T_, 128, 0, stream>>>(z, Wq, bq, Wk, bk, Wv, bv, zq, zk, zv);
    k_attnmid<<<T_, 256, 0, stream>>>(zq, zk, zv, Wo, bo, g2, beta2,
                                      Wm1, bm1, Wm2, bm2, xr);
    k_final<<<1, 128, 0, stream>>>(xr, Wl, bl, outp);
}

// Round 5
// 836.229 us; speedup vs baseline: 16.5970x; 1.1433x over previous
//
#include <hip/hip_runtime.h>
#include <cstdint>

#define T_ 32
#define N_ 5000
#define E_ 80000
#define H_ 128
#define HD_ 512
#define C_ 10

typedef _Float16 f16;
typedef f16 f16x8 __attribute__((ext_vector_type(8)));
typedef f16 f16x4 __attribute__((ext_vector_type(4)));
typedef f16 f16x2 __attribute__((ext_vector_type(2)));
typedef float f32x4 __attribute__((ext_vector_type(4)));

#define LDA 136  // padded LDS leading dim in f16

__device__ inline int addpk(int a, int b) {
    f16x2 x = __builtin_bit_cast(f16x2, a);
    f16x2 y = __builtin_bit_cast(f16x2, b);
    f16x2 r = x + y;
    return __builtin_bit_cast(int, r);
}

__device__ inline float fast_tanh(float x) {
    return 1.0f - 2.0f / (__expf(2.0f * x) + 1.0f);
}

// ---------------- CSR build ----------------
__global__ __launch_bounds__(256) void k_count(const int* __restrict__ ei, int* __restrict__ ptr) {
    int e = blockIdx.x * 256 + threadIdx.x;
    int t = blockIdx.y;
    if (e < E_) {
        int d = ei[(size_t)t * 2 * E_ + E_ + e];
        atomicAdd(&ptr[t * N_ + d], 1);
    }
}

__global__ __launch_bounds__(256) void k_scan(int* __restrict__ ptr, float* __restrict__ dinv,
                                              float* __restrict__ z) {
    int t = blockIdx.x, tid = threadIdx.x;
    __shared__ int part[256];
    int base = t * N_;
    if (tid < 128) z[t * 128 + tid] = 0.0f;   // folded zinit
    int vals[20];
    int sum = 0;
#pragma unroll
    for (int j = 0; j < 20; ++j) {
        int i = tid * 20 + j;
        int c = 0;
        if (i < N_) {
            c = ptr[base + i];
            dinv[base + i] = rsqrtf((float)(c + 1));
        }
        vals[j] = sum;
        sum += c;
    }
    part[tid] = sum;
    __syncthreads();
    for (int off = 1; off < 256; off <<= 1) {
        int v = (tid >= off) ? part[tid - off] : 0;
        __syncthreads();
        part[tid] += v;
        __syncthreads();
    }
    int prev = (tid > 0) ? part[tid - 1] : 0;
#pragma unroll
    for (int j = 0; j < 20; ++j) {
        int i = tid * 20 + j;
        if (i < N_) ptr[base + i] = prev + vals[j];
    }
}

__global__ __launch_bounds__(256) void k_scatter(const int* __restrict__ ei,
                                                 int* __restrict__ ptr,
                                                 uint16_t* __restrict__ col) {
    int e = blockIdx.x * 256 + threadIdx.x;
    int t = blockIdx.y;
    if (e < E_) {
        int s = ei[(size_t)t * 2 * E_ + e];
        int d = ei[(size_t)t * 2 * E_ + E_ + e];
        int pos = atomicAdd(&ptr[t * N_ + d], 1);
        col[(size_t)t * E_ + pos] = (uint16_t)s;
    }
}

// ---------------- weight prep: Wt[l][c][k] = (f16)W_l[k][c] ----------------
__global__ __launch_bounds__(256) void k_wprep(const float* __restrict__ W0,
                                               const float* __restrict__ W1,
                                               const float* __restrict__ W2,
                                               f16* __restrict__ Wt) {
    const float* W = (blockIdx.x == 0) ? W0 : (blockIdx.x == 1) ? W1 : W2;
    f16* dst = Wt + blockIdx.x * 16384;
    for (int idx = threadIdx.x; idx < 16384; idx += 256) {
        int c = idx >> 7, k = idx & 127;
        dst[idx] = (f16)W[k * 128 + c];
    }
}

// ---------------- MFMA GEMM ----------------
template <bool F32IN>
__global__ __launch_bounds__(256) void k_gemm(const void* __restrict__ in_,
                                              const f16* __restrict__ Wt,  // [c][k]
                                              const float* __restrict__ dinv,
                                              f16* __restrict__ g) {
    __shared__ f16 Ws[128 * LDA];
    __shared__ f16 As[64 * LDA];
    int b = blockIdx.x;
    int t = b & 31;
    int r0 = (b >> 5) * 64;
    int tid = threadIdx.x;

    {
        int c = tid >> 1, hf = tid & 1;
        const f16* src = Wt + c * 128 + hf * 64;
        f16* dst = Ws + c * LDA + hf * 64;
#pragma unroll
        for (int j = 0; j < 8; ++j) *(f16x8*)&dst[j * 8] = *(const f16x8*)&src[j * 8];
    }
    {
        int r = tid >> 2, kq = (tid & 3) * 32;
        bool valid = (r0 + r) < N_;
        f16* dst = As + r * LDA + kq;
        if (F32IN) {
            const float* src = (const float*)in_ + ((size_t)(t * N_ + r0 + r)) * H_ + kq;
#pragma unroll
            for (int j = 0; j < 8; ++j) {
                float4 v = valid ? *(const float4*)&src[j * 4] : make_float4(0.f, 0.f, 0.f, 0.f);
                dst[j * 4 + 0] = (f16)v.x;
                dst[j * 4 + 1] = (f16)v.y;
                dst[j * 4 + 2] = (f16)v.z;
                dst[j * 4 + 3] = (f16)v.w;
            }
        } else {
            const f16* src = (const f16*)in_ + ((size_t)(t * N_ + r0 + r)) * H_ + kq;
#pragma unroll
            for (int j = 0; j < 4; ++j) {
                f16x8 v = {};
                if (valid) v = *(const f16x8*)&src[j * 8];
                *(f16x8*)&dst[j * 8] = v;
            }
        }
    }
    __syncthreads();

    int w = tid >> 6, lane = tid & 63;
    int m = lane & 15, q = lane >> 4;
    int rw = w * 16;
    f32x4 acc[8];
#pragma unroll
    for (int n = 0; n < 8; ++n) acc[n] = (f32x4){0.f, 0.f, 0.f, 0.f};

#pragma unroll
    for (int kb = 0; kb < 4; ++kb) {
        f16x8 aF = *(const f16x8*)&As[(rw + m) * LDA + kb * 32 + q * 8];
#pragma unroll
        for (int n = 0; n < 8; ++n) {
            f16x8 bF = *(const f16x8*)&Ws[(n * 16 + m) * LDA + kb * 32 + q * 8];
            acc[n] = __builtin_amdgcn_mfma_f32_16x16x32_f16(aF, bF, acc[n], 0, 0, 0);
        }
    }
    __syncthreads();

#pragma unroll
    for (int i = 0; i < 4; ++i) {
        int rr = rw + q * 4 + i;
        int gr = r0 + rr;
        float d = dinv[t * N_ + (gr < N_ ? gr : N_ - 1)];
#pragma unroll
        for (int n = 0; n < 8; ++n)
            As[rr * LDA + n * 16 + m] = (f16)(acc[n][i] * d);
    }
    __syncthreads();
    {
        int r = tid >> 2, kq = (tid & 3) * 32;
        if (r0 + r < N_) {
            f16* dst = g + ((size_t)(t * N_ + r0 + r)) * H_ + kq;
            const f16* src = As + r * LDA + kq;
#pragma unroll
            for (int j = 0; j < 4; ++j) *(f16x8*)&dst[j * 8] = *(const f16x8*)&src[j * 8];
        }
    }
}

// ---------------- CSR gather + epilogue: packed f16 accumulate, fast tanh ----------------
// 1-D grid, t = b&31; wave per node; quarter-wave (16 lanes x f16x8) per edge, 4 edges in flight
__global__ __launch_bounds__(256) void k_aggr(const int* __restrict__ ptr,
                                              const uint16_t* __restrict__ col,
                                              const f16* __restrict__ g,
                                              const float* __restrict__ dinv,
                                              const float* __restrict__ b,
                                              f16* __restrict__ out) {
    __shared__ f16 sh[4 * 128];
    int blk = blockIdx.x;
    int t = blk & 31;
    int w = threadIdx.x >> 6;
    int n = (blk >> 5) * 4 + w;
    int lane = threadIdx.x & 63;
    int q = lane >> 4, m = lane & 15;
    int base = t * N_;
    int begin = (n == 0) ? 0 : ptr[base + n - 1];
    int end = ptr[base + n];
    const f16* gg = g + (size_t)base * H_;
    const uint16_t* cl = col + (size_t)t * E_;
    f16x8 acc = {};
    if (q == 0) acc = *(const f16x8*)&gg[(size_t)n * H_ + m * 8];  // self-loop
    for (int i = begin + q; i < end; i += 4) {
        int s = cl[i];
        f16x8 v = *(const f16x8*)&gg[(size_t)s * H_ + m * 8];
        acc += v;  // 4x v_pk_add_f16
    }
    union { f16x8 h; int i32[4]; } u;
    u.h = acc;
#pragma unroll
    for (int j = 0; j < 4; ++j) {
        u.i32[j] = addpk(u.i32[j], __shfl(u.i32[j], lane ^ 16, 64));
        u.i32[j] = addpk(u.i32[j], __shfl(u.i32[j], lane ^ 32, 64));
    }
    if (q == 0) *(f16x8*)&sh[w * 128 + m * 8] = u.h;
    __syncthreads();
    // epilogue: all 64 lanes, 2 features each
    int c = lane * 2;
    float d = dinv[base + n];
    f16x2 hv = *(const f16x2*)&sh[w * 128 + c];
    float v0 = fast_tanh(d * (float)hv[0] + b[c + 0]);
    float v1 = fast_tanh(d * (float)hv[1] + b[c + 1]);
    f16x2 o = {(f16)v0, (f16)v1};
    *(f16x2*)&out[((size_t)base + n) * H_ + c] = o;
}

// ---------------- node-sum: z[t][c] = sum_n h[t][n][c] ----------------
__global__ __launch_bounds__(256) void k_reduce(const f16* __restrict__ h, float* __restrict__ z) {
    int t = blockIdx.x, seg = blockIdx.y;
    int tid = threadIdx.x;
    int rg = tid >> 5;
    int c = (tid & 31) * 4;
    const f16* p = h + (size_t)t * N_ * H_;
    float4 acc = make_float4(0.f, 0.f, 0.f, 0.f);
    int n0 = seg * 500;
    for (int n = n0 + rg; n < n0 + 500; n += 8) {
        f16x4 v = *(const f16x4*)&p[(size_t)n * H_ + c];
        acc.x += (float)v[0]; acc.y += (float)v[1]; acc.z += (float)v[2]; acc.w += (float)v[3];
    }
    __shared__ float4 part[256];
    part[tid] = acc;
    __syncthreads();
    if (rg == 0) {
        float4 s = part[tid];
#pragma unroll
        for (int j = 1; j < 8; ++j) {
            float4 v = part[(j << 5) + tid];
            s.x += v.x; s.y += v.y; s.z += v.z; s.w += v.w;
        }
        atomicAdd(&z[t * H_ + c + 0], s.x);
        atomicAdd(&z[t * H_ + c + 1], s.y);
        atomicAdd(&z[t * H_ + c + 2], s.z);
        atomicAdd(&z[t * H_ + c + 3], s.w);
    }
}

// ---------------- head stage 1: q,k,v ----------------
__global__ __launch_bounds__(128) void k_qkv(const float* __restrict__ z,
                                             const float* __restrict__ Wq, const float* __restrict__ bq,
                                             const float* __restrict__ Wk, const float* __restrict__ bk,
                                             const float* __restrict__ Wv, const float* __restrict__ bv,
                                             float* __restrict__ q, float* __restrict__ k,
                                             float* __restrict__ v) {
    int t = blockIdx.x, c = threadIdx.x;
    __shared__ float zs[128];
    zs[c] = z[t * 128 + c];
    __syncthreads();
    float aq = bq[c], ak = bk[c], av = bv[c];
    for (int kk = 0; kk < 128; ++kk) {
        float zv = zs[kk];
        aq += zv * Wq[(kk << 7) + c];
        ak += zv * Wk[(kk << 7) + c];
        av += zv * Wv[(kk << 7) + c];
    }
    q[t * 128 + c] = aq;
    k[t * 128 + c] = ak;
    v[t * 128 + c] = av;
}

// ---------------- head stage 2 ----------------
__global__ __launch_bounds__(256) void k_attnmid(
    const float* __restrict__ q, const float* __restrict__ k, const float* __restrict__ v,
    const float* __restrict__ Wo, const float* __restrict__ bo,
    const float* __restrict__ g2, const float* __restrict__ beta2,
    const float* __restrict__ Wm1, const float* __restrict__ bm1,
    const float* __restrict__ Wm2, const float* __restrict__ bm2,
    float* __restrict__ xr) {
    int t = blockIdx.x, tid = threadIdx.x;
    __shared__ float Ks[32 * 128], Vs[32 * 128];
    __shared__ float qs[128], sc[8 * 32], xa[128], hid[512], ys[128];
    __shared__ float redA[128], redB[128];

    for (int i = tid; i < 32 * 128; i += 256) { Ks[i] = k[i]; Vs[i] = v[i]; }
    if (tid < 128) qs[tid] = q[t * 128 + tid];
    __syncthreads();

    {
        int h = tid >> 5, s = tid & 31;
        float d = 0.0f;
#pragma unroll
        for (int kk = 0; kk < 16; ++kk)
            d += qs[(h << 4) + kk] * Ks[(s << 7) + (h << 4) + kk];
        sc[tid] = d * 0.25f;
    }
    __syncthreads();
    if (tid < 8) {
        float m = -1e30f;
        for (int s = 0; s < 32; ++s) m = fmaxf(m, sc[(tid << 5) + s]);
        float l = 0.0f;
        for (int s = 0; s < 32; ++s) { float e = __expf(sc[(tid << 5) + s] - m); sc[(tid << 5) + s] = e; l += e; }
        float inv = 1.0f / l;
        for (int s = 0; s < 32; ++s) sc[(tid << 5) + s] *= inv;
    }
    __syncthreads();
    if (tid < 128) {
        int h = tid >> 4;
        float o = 0.0f;
        for (int s = 0; s < 32; ++s) o += sc[(h << 5) + s] * Vs[(s << 7) + tid];
        qs[tid] = o;
    }
    __syncthreads();
    if (tid < 128) {
        float a = bo[tid];
        for (int kk = 0; kk < 128; ++kk) a += qs[kk] * Wo[(kk << 7) + tid];
        xa[tid] = a;
    }
    __syncthreads();
    for (int j = tid; j < 512; j += 256) {
        float a = bm1[j];
        for (int kk = 0; kk < 128; ++kk) a += xa[kk] * Wm1[(kk << 9) + j];
        hid[j] = fmaxf(a, 0.0f);
    }
    __syncthreads();
    if (tid < 128) {
        float a = bm2[tid];
        for (int j = 0; j < 512; ++j) a += hid[j] * Wm2[(j << 7) + tid];
        ys[tid] = xa[tid] + a;
    }
    __syncthreads();
    if (tid < 128) { redA[tid] = ys[tid]; redB[tid] = ys[tid] * ys[tid]; }
    __syncthreads();
    for (int off = 64; off > 0; off >>= 1) {
        if (tid < off) { redA[tid] += redA[tid + off]; redB[tid] += redB[tid + off]; }
        __syncthreads();
    }
    float mu = redA[0] * (1.0f / 128.0f);
    float var = redB[0] * (1.0f / 128.0f) - mu * mu;
    float rs = rsqrtf(var + 1e-5f);
    if (tid < 128) {
        float yv = (ys[tid] - mu) * rs * g2[tid] + beta2[tid];
        xr[t * 128 + tid] = fmaxf(yv, 0.0f);
    }
}

// ---------------- head stage 3 ----------------
__global__ __launch_bounds__(128) void k_final(const float* __restrict__ xr,
                                               const float* __restrict__ Wl,
                                               const float* __restrict__ bl,
                                               float* __restrict__ out) {
    int tid = threadIdx.x;
    __shared__ float pooled[128];
    float s = 0.0f;
    for (int t = 0; t < 32; ++t) s += xr[t * 128 + tid];
    pooled[tid] = s;
    __syncthreads();
    if (tid < C_) {
        float a = bl[tid];
        for (int kk = 0; kk < 128; ++kk) a += pooled[kk] * Wl[kk * C_ + tid];
        out[tid] = a;
    }
}

extern "C" void kernel_launch(void* const* d_in, const int* in_sizes, int n_in,
                              void* d_out, int out_size, void* d_ws, size_t ws_size,
                              hipStream_t stream) {
    const float* x  = (const float*)d_in[0];
    const int*   ei = (const int*)d_in[1];
    const float* W0 = (const float*)d_in[2];  const float* b0 = (const float*)d_in[3];
    const float* W1 = (const float*)d_in[4];  const float* b1 = (const float*)d_in[5];
    const float* W2 = (const float*)d_in[6];  const float* b2 = (const float*)d_in[7];
    const float* Wq = (const float*)d_in[8];  const float* bq = (const float*)d_in[9];
    const float* Wk = (const float*)d_in[10]; const float* bk = (const float*)d_in[11];
    const float* Wv = (const float*)d_in[12]; const float* bv = (const float*)d_in[13];
    const float* Wo = (const float*)d_in[14]; const float* bo = (const float*)d_in[15];
    const float* g2 = (const float*)d_in[16]; const float* beta2 = (const float*)d_in[17];
    const float* Wm1 = (const float*)d_in[18]; const float* bm1 = (const float*)d_in[19];
    const float* Wm2 = (const float*)d_in[20]; const float* bm2 = (const float*)d_in[21];
    const float* Wl = (const float*)d_in[22]; const float* bl = (const float*)d_in[23];
    float* outp = (float*)d_out;

    const size_t BIG = (size_t)T_ * N_ * H_;
    char* ws = (char*)d_ws;
    float*    dinv = (float*)(ws);
    int*      ptr  = (int*)(ws + 640000);
    uint16_t* col  = (uint16_t*)(ws + 1280000);
    f16*      Wt   = (f16*)(ws + 6400000);
    f16*      P16  = (f16*)(ws + 6498304);
    f16*      Q16  = P16 + BIG;
    float*    z    = (float*)(Q16 + BIG);
    float*    zq   = z + 4096;
    float*    zk   = zq + 4096;
    float*    zv   = zk + 4096;
    float*    xr   = zv + 4096;

    hipMemsetAsync(ptr, 0, T_ * N_ * sizeof(int), stream);
    k_wprep<<<3, 256, 0, stream>>>(W0, W1, W2, Wt);
    k_count<<<dim3((E_ + 255) / 256, T_), 256, 0, stream>>>(ei, ptr);
    k_scan<<<T_, 256, 0, stream>>>(ptr, dinv, z);
    k_scatter<<<dim3((E_ + 255) / 256, T_), 256, 0, stream>>>(ei, ptr, col);

    const float* bl_[3] = {b0, b1, b2};
    k_gemm<true><<<79 * 32, 256, 0, stream>>>(x, Wt, dinv, P16);
    k_aggr<<<(N_ / 4) * 32, 256, 0, stream>>>(ptr, col, P16, dinv, bl_[0], Q16);
    k_gemm<false><<<79 * 32, 256, 0, stream>>>(Q16, Wt + 16384, dinv, P16);
    k_aggr<<<(N_ / 4) * 32, 256, 0, stream>>>(ptr, col, P16, dinv, bl_[1], Q16);
    k_gemm<false><<<79 * 32, 256, 0, stream>>>(Q16, Wt + 32768, dinv, P16);
    k_aggr<<<(N_ / 4) * 32, 256, 0, stream>>>(ptr, col, P16, dinv, bl_[2], Q16);

    k_reduce<<<dim3(T_, 10), 256, 0, stream>>>(Q16, z);

    k_qkv<<<T_, 128, 0, stream>>>(z, Wq, bq, Wk, bk, Wv, bv, zq, zk, zv);
    k_attnmid<<<T_, 256, 0, stream>>>(zq, zk, zv, Wo, bo, g2, beta2,
                                      Wm1, bm1, Wm2, bm2, xr);
    k_final<<<1, 128, 0, stream>>>(xr, Wl, bl, outp);
}

// Round 6
// 830.955 us; speedup vs baseline: 16.7024x; 1.0063x over previous
//
#include <hip/hip_runtime.h>
#include <cstdint>

#define T_ 32
#define N_ 5000
#define E_ 80000
#define H_ 128
#define HD_ 512
#define C_ 10

typedef _Float16 f16;
typedef f16 f16x8 __attribute__((ext_vector_type(8)));
typedef f16 f16x4 __attribute__((ext_vector_type(4)));
typedef f16 f16x2 __attribute__((ext_vector_type(2)));
typedef float f32x4 __attribute__((ext_vector_type(4)));

#define LDA 136  // padded LDS leading dim in f16
#define EPB 1024 // edges per block in CSR build
#define NCB 79   // ceil(E_/EPB)

__device__ inline int addpk(int a, int b) {
    f16x2 x = __builtin_bit_cast(f16x2, a);
    f16x2 y = __builtin_bit_cast(f16x2, b);
    f16x2 r = x + y;
    return __builtin_bit_cast(int, r);
}

__device__ inline float fast_tanh(float x) {
    return 1.0f - 2.0f / (__expf(2.0f * x) + 1.0f);
}

// ---------------- CSR build (XCD-affine: t = blk & 31) ----------------
__global__ __launch_bounds__(256) void k_count(const int* __restrict__ ei, int* __restrict__ ptr) {
    int blk = blockIdx.x;
    int t = blk & 31;
    int e0 = (blk >> 5) * EPB + threadIdx.x * 4;
    const int* dst = ei + (size_t)t * 2 * E_ + E_;
    int* p = ptr + t * N_;
    if (e0 + 3 < E_) {
        int4 d = *(const int4*)&dst[e0];
        atomicAdd(&p[d.x], 1);
        atomicAdd(&p[d.y], 1);
        atomicAdd(&p[d.z], 1);
        atomicAdd(&p[d.w], 1);
    } else {
        for (int e = e0; e < E_; ++e) atomicAdd(&p[dst[e]], 1);
    }
}

__global__ __launch_bounds__(256) void k_scan(int* __restrict__ ptr, float* __restrict__ dinv,
                                              float* __restrict__ z) {
    int t = blockIdx.x, tid = threadIdx.x;
    __shared__ int part[256];
    int base = t * N_;
    if (tid < 128) z[t * 128 + tid] = 0.0f;   // folded zinit
    int vals[20];
    int sum = 0;
#pragma unroll
    for (int j = 0; j < 20; ++j) {
        int i = tid * 20 + j;
        int c = 0;
        if (i < N_) {
            c = ptr[base + i];
            dinv[base + i] = rsqrtf((float)(c + 1));
        }
        vals[j] = sum;
        sum += c;
    }
    part[tid] = sum;
    __syncthreads();
    for (int off = 1; off < 256; off <<= 1) {
        int v = (tid >= off) ? part[tid - off] : 0;
        __syncthreads();
        part[tid] += v;
        __syncthreads();
    }
    int prev = (tid > 0) ? part[tid - 1] : 0;
#pragma unroll
    for (int j = 0; j < 20; ++j) {
        int i = tid * 20 + j;
        if (i < N_) ptr[base + i] = prev + vals[j];
    }
}

__global__ __launch_bounds__(256) void k_scatter(const int* __restrict__ ei,
                                                 int* __restrict__ ptr,
                                                 uint16_t* __restrict__ col) {
    int blk = blockIdx.x;
    int t = blk & 31;
    int e0 = (blk >> 5) * EPB + threadIdx.x * 4;
    const int* src = ei + (size_t)t * 2 * E_;
    const int* dst = src + E_;
    int* p = ptr + t * N_;
    uint16_t* cl = col + (size_t)t * E_;
    if (e0 + 3 < E_) {
        int4 s = *(const int4*)&src[e0];
        int4 d = *(const int4*)&dst[e0];
        cl[atomicAdd(&p[d.x], 1)] = (uint16_t)s.x;
        cl[atomicAdd(&p[d.y], 1)] = (uint16_t)s.y;
        cl[atomicAdd(&p[d.z], 1)] = (uint16_t)s.z;
        cl[atomicAdd(&p[d.w], 1)] = (uint16_t)s.w;
    } else {
        for (int e = e0; e < E_; ++e)
            cl[atomicAdd(&p[dst[e]], 1)] = (uint16_t)src[e];
    }
}

// ---------------- weight prep: Wt[l][c][k] = (f16)W_l[k][c] ----------------
__global__ __launch_bounds__(256) void k_wprep(const float* __restrict__ W0,
                                               const float* __restrict__ W1,
                                               const float* __restrict__ W2,
                                               f16* __restrict__ Wt) {
    const float* W = (blockIdx.x == 0) ? W0 : (blockIdx.x == 1) ? W1 : W2;
    f16* dst = Wt + blockIdx.x * 16384;
    for (int idx = threadIdx.x; idx < 16384; idx += 256) {
        int c = idx >> 7, k = idx & 127;
        dst[idx] = (f16)W[k * 128 + c];
    }
}

// ---------------- MFMA GEMM ----------------
template <bool F32IN>
__global__ __launch_bounds__(256) void k_gemm(const void* __restrict__ in_,
                                              const f16* __restrict__ Wt,  // [c][k]
                                              const float* __restrict__ dinv,
                                              f16* __restrict__ g) {
    __shared__ f16 Ws[128 * LDA];
    __shared__ f16 As[64 * LDA];
    int b = blockIdx.x;
    int t = b & 31;
    int r0 = (b >> 5) * 64;
    int tid = threadIdx.x;

    {
        int c = tid >> 1, hf = tid & 1;
        const f16* src = Wt + c * 128 + hf * 64;
        f16* dst = Ws + c * LDA + hf * 64;
#pragma unroll
        for (int j = 0; j < 8; ++j) *(f16x8*)&dst[j * 8] = *(const f16x8*)&src[j * 8];
    }
    {
        int r = tid >> 2, kq = (tid & 3) * 32;
        bool valid = (r0 + r) < N_;
        f16* dst = As + r * LDA + kq;
        if (F32IN) {
            const float* src = (const float*)in_ + ((size_t)(t * N_ + r0 + r)) * H_ + kq;
#pragma unroll
            for (int j = 0; j < 8; ++j) {
                float4 v = valid ? *(const float4*)&src[j * 4] : make_float4(0.f, 0.f, 0.f, 0.f);
                dst[j * 4 + 0] = (f16)v.x;
                dst[j * 4 + 1] = (f16)v.y;
                dst[j * 4 + 2] = (f16)v.z;
                dst[j * 4 + 3] = (f16)v.w;
            }
        } else {
            const f16* src = (const f16*)in_ + ((size_t)(t * N_ + r0 + r)) * H_ + kq;
#pragma unroll
            for (int j = 0; j < 4; ++j) {
                f16x8 v = {};
                if (valid) v = *(const f16x8*)&src[j * 8];
                *(f16x8*)&dst[j * 8] = v;
            }
        }
    }
    __syncthreads();

    int w = tid >> 6, lane = tid & 63;
    int m = lane & 15, q = lane >> 4;
    int rw = w * 16;
    f32x4 acc[8];
#pragma unroll
    for (int n = 0; n < 8; ++n) acc[n] = (f32x4){0.f, 0.f, 0.f, 0.f};

#pragma unroll
    for (int kb = 0; kb < 4; ++kb) {
        f16x8 aF = *(const f16x8*)&As[(rw + m) * LDA + kb * 32 + q * 8];
#pragma unroll
        for (int n = 0; n < 8; ++n) {
            f16x8 bF = *(const f16x8*)&Ws[(n * 16 + m) * LDA + kb * 32 + q * 8];
            acc[n] = __builtin_amdgcn_mfma_f32_16x16x32_f16(aF, bF, acc[n], 0, 0, 0);
        }
    }
    __syncthreads();

#pragma unroll
    for (int i = 0; i < 4; ++i) {
        int rr = rw + q * 4 + i;
        int gr = r0 + rr;
        float d = dinv[t * N_ + (gr < N_ ? gr : N_ - 1)];
#pragma unroll
        for (int n = 0; n < 8; ++n)
            As[rr * LDA + n * 16 + m] = (f16)(acc[n][i] * d);
    }
    __syncthreads();
    {
        int r = tid >> 2, kq = (tid & 3) * 32;
        if (r0 + r < N_) {
            f16* dst = g + ((size_t)(t * N_ + r0 + r)) * H_ + kq;
            const f16* src = As + r * LDA + kq;
#pragma unroll
            for (int j = 0; j < 4; ++j) *(f16x8*)&dst[j * 8] = *(const f16x8*)&src[j * 8];
        }
    }
}

// ---------------- CSR gather + epilogue: packed f16 accumulate, fast tanh ----------------
__global__ __launch_bounds__(256) void k_aggr(const int* __restrict__ ptr,
                                              const uint16_t* __restrict__ col,
                                              const f16* __restrict__ g,
                                              const float* __restrict__ dinv,
                                              const float* __restrict__ b,
                                              f16* __restrict__ out) {
    __shared__ f16 sh[4 * 128];
    int blk = blockIdx.x;
    int t = blk & 31;
    int w = threadIdx.x >> 6;
    int n = (blk >> 5) * 4 + w;
    int lane = threadIdx.x & 63;
    int q = lane >> 4, m = lane & 15;
    int base = t * N_;
    int begin = (n == 0) ? 0 : ptr[base + n - 1];
    int end = ptr[base + n];
    const f16* gg = g + (size_t)base * H_;
    const uint16_t* cl = col + (size_t)t * E_;
    f16x8 acc = {};
    if (q == 0) acc = *(const f16x8*)&gg[(size_t)n * H_ + m * 8];  // self-loop
    for (int i = begin + q; i < end; i += 4) {
        int s = cl[i];
        f16x8 v = *(const f16x8*)&gg[(size_t)s * H_ + m * 8];
        acc += v;  // 4x v_pk_add_f16
    }
    union { f16x8 h; int i32[4]; } u;
    u.h = acc;
#pragma unroll
    for (int j = 0; j < 4; ++j) {
        u.i32[j] = addpk(u.i32[j], __shfl(u.i32[j], lane ^ 16, 64));
        u.i32[j] = addpk(u.i32[j], __shfl(u.i32[j], lane ^ 32, 64));
    }
    if (q == 0) *(f16x8*)&sh[w * 128 + m * 8] = u.h;
    __syncthreads();
    int c = lane * 2;
    float d = dinv[base + n];
    f16x2 hv = *(const f16x2*)&sh[w * 128 + c];
    float v0 = fast_tanh(d * (float)hv[0] + b[c + 0]);
    float v1 = fast_tanh(d * (float)hv[1] + b[c + 1]);
    f16x2 o = {(f16)v0, (f16)v1};
    *(f16x2*)&out[((size_t)base + n) * H_ + c] = o;
}

// ---------------- node-sum: z[t][c] = sum_n h[t][n][c] ----------------
__global__ __launch_bounds__(256) void k_reduce(const f16* __restrict__ h, float* __restrict__ z) {
    int t = blockIdx.x, seg = blockIdx.y;
    int tid = threadIdx.x;
    int rg = tid >> 5;
    int c = (tid & 31) * 4;
    const f16* p = h + (size_t)t * N_ * H_;
    float4 acc = make_float4(0.f, 0.f, 0.f, 0.f);
    int n0 = seg * 500;
    for (int n = n0 + rg; n < n0 + 500; n += 8) {
        f16x4 v = *(const f16x4*)&p[(size_t)n * H_ + c];
        acc.x += (float)v[0]; acc.y += (float)v[1]; acc.z += (float)v[2]; acc.w += (float)v[3];
    }
    __shared__ float4 part[256];
    part[tid] = acc;
    __syncthreads();
    if (rg == 0) {
        float4 s = part[tid];
#pragma unroll
        for (int j = 1; j < 8; ++j) {
            float4 v = part[(j << 5) + tid];
            s.x += v.x; s.y += v.y; s.z += v.z; s.w += v.w;
        }
        atomicAdd(&z[t * H_ + c + 0], s.x);
        atomicAdd(&z[t * H_ + c + 1], s.y);
        atomicAdd(&z[t * H_ + c + 2], s.z);
        atomicAdd(&z[t * H_ + c + 3], s.w);
    }
}

// ---------------- head stage 1: q,k,v ----------------
__global__ __launch_bounds__(128) void k_qkv(const float* __restrict__ z,
                                             const float* __restrict__ Wq, const float* __restrict__ bq,
                                             const float* __restrict__ Wk, const float* __restrict__ bk,
                                             const float* __restrict__ Wv, const float* __restrict__ bv,
                                             float* __restrict__ q, float* __restrict__ k,
                                             float* __restrict__ v) {
    int t = blockIdx.x, c = threadIdx.x;
    __shared__ float zs[128];
    zs[c] = z[t * 128 + c];
    __syncthreads();
    float aq = bq[c], ak = bk[c], av = bv[c];
    for (int kk = 0; kk < 128; ++kk) {
        float zv = zs[kk];
        aq += zv * Wq[(kk << 7) + c];
        ak += zv * Wk[(kk << 7) + c];
        av += zv * Wv[(kk << 7) + c];
    }
    q[t * 128 + c] = aq;
    k[t * 128 + c] = ak;
    v[t * 128 + c] = av;
}

// ---------------- head stage 2 ----------------
__global__ __launch_bounds__(256) void k_attnmid(
    const float* __restrict__ q, const float* __restrict__ k, const float* __restrict__ v,
    const float* __restrict__ Wo, const float* __restrict__ bo,
    const float* __restrict__ g2, const float* __restrict__ beta2,
    const float* __restrict__ Wm1, const float* __restrict__ bm1,
    const float* __restrict__ Wm2, const float* __restrict__ bm2,
    float* __restrict__ xr) {
    int t = blockIdx.x, tid = threadIdx.x;
    __shared__ float Ks[32 * 128], Vs[32 * 128];
    __shared__ float qs[128], sc[8 * 32], xa[128], hid[512], ys[128];
    __shared__ float redA[128], redB[128];

    for (int i = tid; i < 32 * 128; i += 256) { Ks[i] = k[i]; Vs[i] = v[i]; }
    if (tid < 128) qs[tid] = q[t * 128 + tid];
    __syncthreads();

    {
        int h = tid >> 5, s = tid & 31;
        float d = 0.0f;
#pragma unroll
        for (int kk = 0; kk < 16; ++kk)
            d += qs[(h << 4) + kk] * Ks[(s << 7) + (h << 4) + kk];
        sc[tid] = d * 0.25f;
    }
    __syncthreads();
    if (tid < 8) {
        float m = -1e30f;
        for (int s = 0; s < 32; ++s) m = fmaxf(m, sc[(tid << 5) + s]);
        float l = 0.0f;
        for (int s = 0; s < 32; ++s) { float e = __expf(sc[(tid << 5) + s] - m); sc[(tid << 5) + s] = e; l += e; }
        float inv = 1.0f / l;
        for (int s = 0; s < 32; ++s) sc[(tid << 5) + s] *= inv;
    }
    __syncthreads();
    if (tid < 128) {
        int h = tid >> 4;
        float o = 0.0f;
        for (int s = 0; s < 32; ++s) o += sc[(h << 5) + s] * Vs[(s << 7) + tid];
        qs[tid] = o;
    }
    __syncthreads();
    if (tid < 128) {
        float a = bo[tid];
        for (int kk = 0; kk < 128; ++kk) a += qs[kk] * Wo[(kk << 7) + tid];
        xa[tid] = a;
    }
    __syncthreads();
    for (int j = tid; j < 512; j += 256) {
        float a = bm1[j];
        for (int kk = 0; kk < 128; ++kk) a += xa[kk] * Wm1[(kk << 9) + j];
        hid[j] = fmaxf(a, 0.0f);
    }
    __syncthreads();
    if (tid < 128) {
        float a = bm2[tid];
        for (int j = 0; j < 512; ++j) a += hid[j] * Wm2[(j << 7) + tid];
        ys[tid] = xa[tid] + a;
    }
    __syncthreads();
    if (tid < 128) { redA[tid] = ys[tid]; redB[tid] = ys[tid] * ys[tid]; }
    __syncthreads();
    for (int off = 64; off > 0; off >>= 1) {
        if (tid < off) { redA[tid] += redA[tid + off]; redB[tid] += redB[tid + off]; }
        __syncthreads();
    }
    float mu = redA[0] * (1.0f / 128.0f);
    float var = redB[0] * (1.0f / 128.0f) - mu * mu;
    float rs = rsqrtf(var + 1e-5f);
    if (tid < 128) {
        float yv = (ys[tid] - mu) * rs * g2[tid] + beta2[tid];
        xr[t * 128 + tid] = fmaxf(yv, 0.0f);
    }
}

// ---------------- head stage 3 ----------------
__global__ __launch_bounds__(128) void k_final(const float* __restrict__ xr,
                                               const float* __restrict__ Wl,
                                               const float* __restrict__ bl,
                                               float* __restrict__ out) {
    int tid = threadIdx.x;
    __shared__ float pooled[128];
    float s = 0.0f;
    for (int t = 0; t < 32; ++t) s += xr[t * 128 + tid];
    pooled[tid] = s;
    __syncthreads();
    if (tid < C_) {
        float a = bl[tid];
        for (int kk = 0; kk < 128; ++kk) a += pooled[kk] * Wl[kk * C_ + tid];
        out[tid] = a;
    }
}

extern "C" void kernel_launch(void* const* d_in, const int* in_sizes, int n_in,
                              void* d_out, int out_size, void* d_ws, size_t ws_size,
                              hipStream_t stream) {
    const float* x  = (const float*)d_in[0];
    const int*   ei = (const int*)d_in[1];
    const float* W0 = (const float*)d_in[2];  const float* b0 = (const float*)d_in[3];
    const float* W1 = (const float*)d_in[4];  const float* b1 = (const float*)d_in[5];
    const float* W2 = (const float*)d_in[6];  const float* b2 = (const float*)d_in[7];
    const float* Wq = (const float*)d_in[8];  const float* bq = (const float*)d_in[9];
    const float* Wk = (const float*)d_in[10]; const float* bk = (const float*)d_in[11];
    const float* Wv = (const float*)d_in[12]; const float* bv = (const float*)d_in[13];
    const float* Wo = (const float*)d_in[14]; const float* bo = (const float*)d_in[15];
    const float* g2 = (const float*)d_in[16]; const float* beta2 = (const float*)d_in[17];
    const float* Wm1 = (const float*)d_in[18]; const float* bm1 = (const float*)d_in[19];
    const float* Wm2 = (const float*)d_in[20]; const float* bm2 = (const float*)d_in[21];
    const float* Wl = (const float*)d_in[22]; const float* bl = (const float*)d_in[23];
    float* outp = (float*)d_out;

    const size_t BIG = (size_t)T_ * N_ * H_;
    char* ws = (char*)d_ws;
    float*    dinv = (float*)(ws);
    int*      ptr  = (int*)(ws + 640000);
    uint16_t* col  = (uint16_t*)(ws + 1280000);
    f16*      Wt   = (f16*)(ws + 6400000);
    f16*      P16  = (f16*)(ws + 6498304);
    f16*      Q16  = P16 + BIG;
    float*    z    = (float*)(Q16 + BIG);
    float*    zq   = z + 4096;
    float*    zk   = zq + 4096;
    float*    zv   = zk + 4096;
    float*    xr   = zv + 4096;

    hipMemsetAsync(ptr, 0, T_ * N_ * sizeof(int), stream);
    k_wprep<<<3, 256, 0, stream>>>(W0, W1, W2, Wt);
    k_count<<<NCB * 32, 256, 0, stream>>>(ei, ptr);
    k_scan<<<T_, 256, 0, stream>>>(ptr, dinv, z);
    k_scatter<<<NCB * 32, 256, 0, stream>>>(ei, ptr, col);

    const float* bl_[3] = {b0, b1, b2};
    k_gemm<true><<<79 * 32, 256, 0, stream>>>(x, Wt, dinv, P16);
    k_aggr<<<(N_ / 4) * 32, 256, 0, stream>>>(ptr, col, P16, dinv, bl_[0], Q16);
    k_gemm<false><<<79 * 32, 256, 0, stream>>>(Q16, Wt + 16384, dinv, P16);
    k_aggr<<<(N_ / 4) * 32, 256, 0, stream>>>(ptr, col, P16, dinv, bl_[1], Q16);
    k_gemm<false><<<79 * 32, 256, 0, stream>>>(Q16, Wt + 32768, dinv, P16);
    k_aggr<<<(N_ / 4) * 32, 256, 0, stream>>>(ptr, col, P16, dinv, bl_[2], Q16);

    k_reduce<<<dim3(T_, 10), 256, 0, stream>>>(Q16, z);

    k_qkv<<<T_, 128, 0, stream>>>(z, Wq, bq, Wk, bk, Wv, bv, zq, zk, zv);
    k_attnmid<<<T_, 256, 0, stream>>>(zq, zk, zv, Wo, bo, g2, beta2,
                                      Wm1, bm1, Wm2, bm2, xr);
    k_final<<<1, 128, 0, stream>>>(xr, Wl, bl, outp);
}

// Round 7
// 708.628 us; speedup vs baseline: 19.5856x; 1.1726x over previous
//
#include <hip/hip_runtime.h>
#include <cstdint>

#define T_ 32
#define N_ 5000
#define E_ 80000
#define H_ 128
#define HD_ 512
#define C_ 10

typedef _Float16 f16;
typedef f16 f16x8 __attribute__((ext_vector_type(8)));
typedef f16 f16x4 __attribute__((ext_vector_type(4)));
typedef f16 f16x2 __attribute__((ext_vector_type(2)));
typedef float f32x4 __attribute__((ext_vector_type(4)));

#define LDA 136   // padded LDS leading dim in f16
#define NB_ 8     // CSR-build blocks per graph
#define EPS_ (E_ / NB_)  // 10000 edges per block

__device__ inline int addpk(int a, int b) {
    f16x2 x = __builtin_bit_cast(f16x2, a);
    f16x2 y = __builtin_bit_cast(f16x2, b);
    f16x2 r = x + y;
    return __builtin_bit_cast(int, r);
}

__device__ inline float fast_tanh(float x) {
    return 1.0f - 2.0f / (__expf(2.0f * x) + 1.0f);
}

// ---------------- CSR build, LDS-atomic (no global atomics) ----------------
// part[t][seg][n]: per-segment counts, later overwritten with per-segment cursor bases
__global__ __launch_bounds__(256) void k_count(const int* __restrict__ ei, int* __restrict__ part) {
    __shared__ int cnt[N_];
    int blk = blockIdx.x;
    int t = blk & 31, seg = blk >> 5;
    int tid = threadIdx.x;
    for (int i = tid; i < N_; i += 256) cnt[i] = 0;
    __syncthreads();
    const int* dst = ei + (size_t)t * 2 * E_ + E_ + seg * EPS_;
    for (int e = tid * 4; e < EPS_; e += 1024) {
        int4 d = *(const int4*)&dst[e];
        atomicAdd(&cnt[d.x], 1);
        atomicAdd(&cnt[d.y], 1);
        atomicAdd(&cnt[d.z], 1);
        atomicAdd(&cnt[d.w], 1);
    }
    __syncthreads();
    int* p = part + (t * NB_ + seg) * N_;
    for (int i = tid * 4; i < N_; i += 1024) *(int4*)&p[i] = *(const int4*)&cnt[i];
}

// one block per graph: total counts -> dinv + exclusive starts (ptr) + per-seg bases (in-place)
__global__ __launch_bounds__(256) void k_scan(int* __restrict__ part, int* __restrict__ ptr,
                                              float* __restrict__ dinv, float* __restrict__ z) {
    int t = blockIdx.x, tid = threadIdx.x;
    __shared__ int red[256];
    int base = t * N_;
    if (tid < 128) z[t * 128 + tid] = 0.0f;   // folded zinit
    int* pp = part + t * NB_ * N_;
    int vals[20];
    int sum = 0;
#pragma unroll
    for (int j = 0; j < 20; ++j) {
        int i = tid * 20 + j;
        int c = 0;
        if (i < N_) {
#pragma unroll
            for (int s = 0; s < NB_; ++s) c += pp[s * N_ + i];
            dinv[base + i] = rsqrtf((float)(c + 1));  // +1 self-loop
        }
        vals[j] = sum;
        sum += c;
    }
    red[tid] = sum;
    __syncthreads();
    for (int off = 1; off < 256; off <<= 1) {
        int v = (tid >= off) ? red[tid - off] : 0;
        __syncthreads();
        red[tid] += v;
        __syncthreads();
    }
    int prev = (tid > 0) ? red[tid - 1] : 0;
#pragma unroll
    for (int j = 0; j < 20; ++j) {
        int i = tid * 20 + j;
        if (i < N_) {
            int start = prev + vals[j];
            ptr[base + i] = start;
            int run = start;
#pragma unroll
            for (int s = 0; s < NB_; ++s) {
                int c = pp[s * N_ + i];
                pp[s * N_ + i] = run;
                run += c;
            }
        }
    }
}

__global__ __launch_bounds__(256) void k_scatter(const int* __restrict__ ei,
                                                 const int* __restrict__ part,
                                                 uint16_t* __restrict__ col) {
    __shared__ int cur[N_];
    int blk = blockIdx.x;
    int t = blk & 31, seg = blk >> 5;
    int tid = threadIdx.x;
    const int* off = part + (t * NB_ + seg) * N_;
    for (int i = tid * 4; i < N_; i += 1024) *(int4*)&cur[i] = *(const int4*)&off[i];
    __syncthreads();
    const int* src = ei + (size_t)t * 2 * E_ + seg * EPS_;
    const int* dst = src + E_;
    uint16_t* cl = col + (size_t)t * E_;
    for (int e = tid * 4; e < EPS_; e += 1024) {
        int4 s4 = *(const int4*)&src[e];
        int4 d4 = *(const int4*)&dst[e];
        cl[atomicAdd(&cur[d4.x], 1)] = (uint16_t)s4.x;
        cl[atomicAdd(&cur[d4.y], 1)] = (uint16_t)s4.y;
        cl[atomicAdd(&cur[d4.z], 1)] = (uint16_t)s4.z;
        cl[atomicAdd(&cur[d4.w], 1)] = (uint16_t)s4.w;
    }
}

// ---------------- weight prep: Wt[l][c][k] = (f16)W_l[k][c] ----------------
__global__ __launch_bounds__(256) void k_wprep(const float* __restrict__ W0,
                                               const float* __restrict__ W1,
                                               const float* __restrict__ W2,
                                               f16* __restrict__ Wt) {
    const float* W = (blockIdx.x == 0) ? W0 : (blockIdx.x == 1) ? W1 : W2;
    f16* dst = Wt + blockIdx.x * 16384;
    for (int idx = threadIdx.x; idx < 16384; idx += 256) {
        int c = idx >> 7, k = idx & 127;
        dst[idx] = (f16)W[k * 128 + c];
    }
}

// ---------------- MFMA GEMM ----------------
template <bool F32IN>
__global__ __launch_bounds__(256) void k_gemm(const void* __restrict__ in_,
                                              const f16* __restrict__ Wt,  // [c][k]
                                              const float* __restrict__ dinv,
                                              f16* __restrict__ g) {
    __shared__ f16 Ws[128 * LDA];
    __shared__ f16 As[64 * LDA];
    int b = blockIdx.x;
    int t = b & 31;
    int r0 = (b >> 5) * 64;
    int tid = threadIdx.x;

    {
        int c = tid >> 1, hf = tid & 1;
        const f16* src = Wt + c * 128 + hf * 64;
        f16* dst = Ws + c * LDA + hf * 64;
#pragma unroll
        for (int j = 0; j < 8; ++j) *(f16x8*)&dst[j * 8] = *(const f16x8*)&src[j * 8];
    }
    {
        int r = tid >> 2, kq = (tid & 3) * 32;
        bool valid = (r0 + r) < N_;
        f16* dst = As + r * LDA + kq;
        if (F32IN) {
            const float* src = (const float*)in_ + ((size_t)(t * N_ + r0 + r)) * H_ + kq;
#pragma unroll
            for (int j = 0; j < 8; ++j) {
                float4 v = valid ? *(const float4*)&src[j * 4] : make_float4(0.f, 0.f, 0.f, 0.f);
                dst[j * 4 + 0] = (f16)v.x;
                dst[j * 4 + 1] = (f16)v.y;
                dst[j * 4 + 2] = (f16)v.z;
                dst[j * 4 + 3] = (f16)v.w;
            }
        } else {
            const f16* src = (const f16*)in_ + ((size_t)(t * N_ + r0 + r)) * H_ + kq;
#pragma unroll
            for (int j = 0; j < 4; ++j) {
                f16x8 v = {};
                if (valid) v = *(const f16x8*)&src[j * 8];
                *(f16x8*)&dst[j * 8] = v;
            }
        }
    }
    __syncthreads();

    int w = tid >> 6, lane = tid & 63;
    int m = lane & 15, q = lane >> 4;
    int rw = w * 16;
    f32x4 acc[8];
#pragma unroll
    for (int n = 0; n < 8; ++n) acc[n] = (f32x4){0.f, 0.f, 0.f, 0.f};

#pragma unroll
    for (int kb = 0; kb < 4; ++kb) {
        f16x8 aF = *(const f16x8*)&As[(rw + m) * LDA + kb * 32 + q * 8];
#pragma unroll
        for (int n = 0; n < 8; ++n) {
            f16x8 bF = *(const f16x8*)&Ws[(n * 16 + m) * LDA + kb * 32 + q * 8];
            acc[n] = __builtin_amdgcn_mfma_f32_16x16x32_f16(aF, bF, acc[n], 0, 0, 0);
        }
    }
    __syncthreads();

#pragma unroll
    for (int i = 0; i < 4; ++i) {
        int rr = rw + q * 4 + i;
        int gr = r0 + rr;
        float d = dinv[t * N_ + (gr < N_ ? gr : N_ - 1)];
#pragma unroll
        for (int n = 0; n < 8; ++n)
            As[rr * LDA + n * 16 + m] = (f16)(acc[n][i] * d);
    }
    __syncthreads();
    {
        int r = tid >> 2, kq = (tid & 3) * 32;
        if (r0 + r < N_) {
            f16* dst = g + ((size_t)(t * N_ + r0 + r)) * H_ + kq;
            const f16* src = As + r * LDA + kq;
#pragma unroll
            for (int j = 0; j < 4; ++j) *(f16x8*)&dst[j * 8] = *(const f16x8*)&src[j * 8];
        }
    }
}

// ---------------- CSR gather + epilogue: packed f16 accumulate, fast tanh ----------------
__global__ __launch_bounds__(256) void k_aggr(const int* __restrict__ ptr,
                                              const uint16_t* __restrict__ col,
                                              const f16* __restrict__ g,
                                              const float* __restrict__ dinv,
                                              const float* __restrict__ b,
                                              f16* __restrict__ out) {
    __shared__ f16 sh[4 * 128];
    int blk = blockIdx.x;
    int t = blk & 31;
    int w = threadIdx.x >> 6;
    int n = (blk >> 5) * 4 + w;
    int lane = threadIdx.x & 63;
    int q = lane >> 4, m = lane & 15;
    int base = t * N_;
    int begin = ptr[base + n];
    int end = (n == N_ - 1) ? E_ : ptr[base + n + 1];
    const f16* gg = g + (size_t)base * H_;
    const uint16_t* cl = col + (size_t)t * E_;
    f16x8 acc = {};
    if (q == 0) acc = *(const f16x8*)&gg[(size_t)n * H_ + m * 8];  // self-loop
    for (int i = begin + q; i < end; i += 4) {
        int s = cl[i];
        f16x8 v = *(const f16x8*)&gg[(size_t)s * H_ + m * 8];
        acc += v;  // 4x v_pk_add_f16
    }
    union { f16x8 h; int i32[4]; } u;
    u.h = acc;
#pragma unroll
    for (int j = 0; j < 4; ++j) {
        u.i32[j] = addpk(u.i32[j], __shfl(u.i32[j], lane ^ 16, 64));
        u.i32[j] = addpk(u.i32[j], __shfl(u.i32[j], lane ^ 32, 64));
    }
    if (q == 0) *(f16x8*)&sh[w * 128 + m * 8] = u.h;
    __syncthreads();
    int c = lane * 2;
    float d = dinv[base + n];
    f16x2 hv = *(const f16x2*)&sh[w * 128 + c];
    float v0 = fast_tanh(d * (float)hv[0] + b[c + 0]);
    float v1 = fast_tanh(d * (float)hv[1] + b[c + 1]);
    f16x2 o = {(f16)v0, (f16)v1};
    *(f16x2*)&out[((size_t)base + n) * H_ + c] = o;
}

// ---------------- node-sum: z[t][c] = sum_n h[t][n][c] ----------------
__global__ __launch_bounds__(256) void k_reduce(const f16* __restrict__ h, float* __restrict__ z) {
    int t = blockIdx.x, seg = blockIdx.y;
    int tid = threadIdx.x;
    int rg = tid >> 5;
    int c = (tid & 31) * 4;
    const f16* p = h + (size_t)t * N_ * H_;
    float4 acc = make_float4(0.f, 0.f, 0.f, 0.f);
    int n0 = seg * 500;
    for (int n = n0 + rg; n < n0 + 500; n += 8) {
        f16x4 v = *(const f16x4*)&p[(size_t)n * H_ + c];
        acc.x += (float)v[0]; acc.y += (float)v[1]; acc.z += (float)v[2]; acc.w += (float)v[3];
    }
    __shared__ float4 part[256];
    part[tid] = acc;
    __syncthreads();
    if (rg == 0) {
        float4 s = part[tid];
#pragma unroll
        for (int j = 1; j < 8; ++j) {
            float4 v = part[(j << 5) + tid];
            s.x += v.x; s.y += v.y; s.z += v.z; s.w += v.w;
        }
        atomicAdd(&z[t * H_ + c + 0], s.x);
        atomicAdd(&z[t * H_ + c + 1], s.y);
        atomicAdd(&z[t * H_ + c + 2], s.z);
        atomicAdd(&z[t * H_ + c + 3], s.w);
    }
}

// ---------------- head stage 1: q,k,v ----------------
__global__ __launch_bounds__(128) void k_qkv(const float* __restrict__ z,
                                             const float* __restrict__ Wq, const float* __restrict__ bq,
                                             const float* __restrict__ Wk, const float* __restrict__ bk,
                                             const float* __restrict__ Wv, const float* __restrict__ bv,
                                             float* __restrict__ q, float* __restrict__ k,
                                             float* __restrict__ v) {
    int t = blockIdx.x, c = threadIdx.x;
    __shared__ float zs[128];
    zs[c] = z[t * 128 + c];
    __syncthreads();
    float aq = bq[c], ak = bk[c], av = bv[c];
    for (int kk = 0; kk < 128; ++kk) {
        float zv = zs[kk];
        aq += zv * Wq[(kk << 7) + c];
        ak += zv * Wk[(kk << 7) + c];
        av += zv * Wv[(kk << 7) + c];
    }
    q[t * 128 + c] = aq;
    k[t * 128 + c] = ak;
    v[t * 128 + c] = av;
}

// ---------------- head stage 2 ----------------
__global__ __launch_bounds__(256) void k_attnmid(
    const float* __restrict__ q, const float* __restrict__ k, const float* __restrict__ v,
    const float* __restrict__ Wo, const float* __restrict__ bo,
    const float* __restrict__ g2, const float* __restrict__ beta2,
    const float* __restrict__ Wm1, const float* __restrict__ bm1,
    const float* __restrict__ Wm2, const float* __restrict__ bm2,
    float* __restrict__ xr) {
    int t = blockIdx.x, tid = threadIdx.x;
    __shared__ float Ks[32 * 128], Vs[32 * 128];
    __shared__ float qs[128], sc[8 * 32], xa[128], hid[512], ys[128];
    __shared__ float redA[128], redB[128];

    for (int i = tid; i < 32 * 128; i += 256) { Ks[i] = k[i]; Vs[i] = v[i]; }
    if (tid < 128) qs[tid] = q[t * 128 + tid];
    __syncthreads();

    {
        int h = tid >> 5, s = tid & 31;
        float d = 0.0f;
#pragma unroll
        for (int kk = 0; kk < 16; ++kk)
            d += qs[(h << 4) + kk] * Ks[(s << 7) + (h << 4) + kk];
        sc[tid] = d * 0.25f;
    }
    __syncthreads();
    if (tid < 8) {
        float m = -1e30f;
        for (int s = 0; s < 32; ++s) m = fmaxf(m, sc[(tid << 5) + s]);
        float l = 0.0f;
        for (int s = 0; s < 32; ++s) { float e = __expf(sc[(tid << 5) + s] - m); sc[(tid << 5) + s] = e; l += e; }
        float inv = 1.0f / l;
        for (int s = 0; s < 32; ++s) sc[(tid << 5) + s] *= inv;
    }
    __syncthreads();
    if (tid < 128) {
        int h = tid >> 4;
        float o = 0.0f;
        for (int s = 0; s < 32; ++s) o += sc[(h << 5) + s] * Vs[(s << 7) + tid];
        qs[tid] = o;
    }
    __syncthreads();
    if (tid < 128) {
        float a = bo[tid];
        for (int kk = 0; kk < 128; ++kk) a += qs[kk] * Wo[(kk << 7) + tid];
        xa[tid] = a;
    }
    __syncthreads();
    for (int j = tid; j < 512; j += 256) {
        float a = bm1[j];
        for (int kk = 0; kk < 128; ++kk) a += xa[kk] * Wm1[(kk << 9) + j];
        hid[j] = fmaxf(a, 0.0f);
    }
    __syncthreads();
    if (tid < 128) {
        float a = bm2[tid];
        for (int j = 0; j < 512; ++j) a += hid[j] * Wm2[(j << 7) + tid];
        ys[tid] = xa[tid] + a;
    }
    __syncthreads();
    if (tid < 128) { redA[tid] = ys[tid]; redB[tid] = ys[tid] * ys[tid]; }
    __syncthreads();
    for (int off = 64; off > 0; off >>= 1) {
        if (tid < off) { redA[tid] += redA[tid + off]; redB[tid] += redB[tid + off]; }
        __syncthreads();
    }
    float mu = redA[0] * (1.0f / 128.0f);
    float var = redB[0] * (1.0f / 128.0f) - mu * mu;
    float rs = rsqrtf(var + 1e-5f);
    if (tid < 128) {
        float yv = (ys[tid] - mu) * rs * g2[tid] + beta2[tid];
        xr[t * 128 + tid] = fmaxf(yv, 0.0f);
    }
}

// ---------------- head stage 3 ----------------
__global__ __launch_bounds__(128) void k_final(const float* __restrict__ xr,
                                               const float* __restrict__ Wl,
                                               const float* __restrict__ bl,
                                               float* __restrict__ out) {
    int tid = threadIdx.x;
    __shared__ float pooled[128];
    float s = 0.0f;
    for (int t = 0; t < 32; ++t) s += xr[t * 128 + tid];
    pooled[tid] = s;
    __syncthreads();
    if (tid < C_) {
        float a = bl[tid];
        for (int kk = 0; kk < 128; ++kk) a += pooled[kk] * Wl[kk * C_ + tid];
        out[tid] = a;
    }
}

extern "C" void kernel_launch(void* const* d_in, const int* in_sizes, int n_in,
                              void* d_out, int out_size, void* d_ws, size_t ws_size,
                              hipStream_t stream) {
    const float* x  = (const float*)d_in[0];
    const int*   ei = (const int*)d_in[1];
    const float* W0 = (const float*)d_in[2];  const float* b0 = (const float*)d_in[3];
    const float* W1 = (const float*)d_in[4];  const float* b1 = (const float*)d_in[5];
    const float* W2 = (const float*)d_in[6];  const float* b2 = (const float*)d_in[7];
    const float* Wq = (const float*)d_in[8];  const float* bq = (const float*)d_in[9];
    const float* Wk = (const float*)d_in[10]; const float* bk = (const float*)d_in[11];
    const float* Wv = (const float*)d_in[12]; const float* bv = (const float*)d_in[13];
    const float* Wo = (const float*)d_in[14]; const float* bo = (const float*)d_in[15];
    const float* g2 = (const float*)d_in[16]; const float* beta2 = (const float*)d_in[17];
    const float* Wm1 = (const float*)d_in[18]; const float* bm1 = (const float*)d_in[19];
    const float* Wm2 = (const float*)d_in[20]; const float* bm2 = (const float*)d_in[21];
    const float* Wl = (const float*)d_in[22]; const float* bl = (const float*)d_in[23];
    float* outp = (float*)d_out;

    const size_t BIG = (size_t)T_ * N_ * H_;
    char* ws = (char*)d_ws;
    float*    dinv = (float*)(ws);
    int*      ptr  = (int*)(ws + 640000);
    uint16_t* col  = (uint16_t*)(ws + 1280000);
    f16*      Wt   = (f16*)(ws + 6400000);
    f16*      P16  = (f16*)(ws + 6498304);
    f16*      Q16  = P16 + BIG;
    float*    z    = (float*)(Q16 + BIG);
    float*    zq   = z + 4096;
    float*    zk   = zq + 4096;
    float*    zv   = zk + 4096;
    float*    xr   = zv + 4096;
    // CSR partial counts/cursor bases alias P16 (only used before first k_gemm)
    int*      part = (int*)P16;   // 32*8*5000 ints = 5.12 MB < 41 MB

    k_wprep<<<3, 256, 0, stream>>>(W0, W1, W2, Wt);
    k_count<<<NB_ * 32, 256, 0, stream>>>(ei, part);
    k_scan<<<T_, 256, 0, stream>>>(part, ptr, dinv, z);
    k_scatter<<<NB_ * 32, 256, 0, stream>>>(ei, part, col);

    const float* bl_[3] = {b0, b1, b2};
    k_gemm<true><<<79 * 32, 256, 0, stream>>>(x, Wt, dinv, P16);
    k_aggr<<<(N_ / 4) * 32, 256, 0, stream>>>(ptr, col, P16, dinv, bl_[0], Q16);
    k_gemm<false><<<79 * 32, 256, 0, stream>>>(Q16, Wt + 16384, dinv, P16);
    k_aggr<<<(N_ / 4) * 32, 256, 0, stream>>>(ptr, col, P16, dinv, bl_[1], Q16);
    k_gemm<false><<<79 * 32, 256, 0, stream>>>(Q16, Wt + 32768, dinv, P16);
    k_aggr<<<(N_ / 4) * 32, 256, 0, stream>>>(ptr, col, P16, dinv, bl_[2], Q16);

    k_reduce<<<dim3(T_, 10), 256, 0, stream>>>(Q16, z);

    k_qkv<<<T_, 128, 0, stream>>>(z, Wq, bq, Wk, bk, Wv, bv, zq, zk, zv);
    k_attnmid<<<T_, 256, 0, stream>>>(zq, zk, zv, Wo, bo, g2, beta2,
                                      Wm1, bm1, Wm2, bm2, xr);
    k_final<<<1, 128, 0, stream>>>(xr, Wl, bl, outp);
}

// Round 8
// 646.960 us; speedup vs baseline: 21.4525x; 1.0953x over previous
//
#include <hip/hip_runtime.h>
#include <cstdint>

#define T_ 32
#define N_ 5000
#define E_ 80000
#define H_ 128
#define HD_ 512
#define C_ 10

typedef _Float16 f16;
typedef f16 f16x8 __attribute__((ext_vector_type(8)));
typedef f16 f16x4 __attribute__((ext_vector_type(4)));
typedef f16 f16x2 __attribute__((ext_vector_type(2)));
typedef float f32x4 __attribute__((ext_vector_type(4)));

#define LDA 136   // padded LDS leading dim in f16
#define NB_ 8     // CSR-build blocks per graph
#define EPS_ (E_ / NB_)  // 10000 edges per block

__device__ inline int addpk(int a, int b) {
    f16x2 x = __builtin_bit_cast(f16x2, a);
    f16x2 y = __builtin_bit_cast(f16x2, b);
    f16x2 r = x + y;
    return __builtin_bit_cast(int, r);
}

__device__ inline float fast_tanh(float x) {
    return 1.0f - 2.0f / (__expf(2.0f * x) + 1.0f);
}

// ---------------- CSR build, LDS-atomic (no global atomics) ----------------
__global__ __launch_bounds__(256) void k_count(const int* __restrict__ ei, int* __restrict__ part) {
    __shared__ int cnt[N_];
    int blk = blockIdx.x;
    int t = blk & 31, seg = blk >> 5;
    int tid = threadIdx.x;
    for (int i = tid; i < N_; i += 256) cnt[i] = 0;
    __syncthreads();
    const int* dst = ei + (size_t)t * 2 * E_ + E_ + seg * EPS_;
    for (int e = tid * 4; e < EPS_; e += 1024) {
        int4 d = *(const int4*)&dst[e];
        atomicAdd(&cnt[d.x], 1);
        atomicAdd(&cnt[d.y], 1);
        atomicAdd(&cnt[d.z], 1);
        atomicAdd(&cnt[d.w], 1);
    }
    __syncthreads();
    int* p = part + (t * NB_ + seg) * N_;
    for (int i = tid * 4; i < N_; i += 1024) *(int4*)&p[i] = *(const int4*)&cnt[i];
}

__global__ __launch_bounds__(256) void k_scan(int* __restrict__ part, int* __restrict__ ptr,
                                              float* __restrict__ dinv, float* __restrict__ z) {
    int t = blockIdx.x, tid = threadIdx.x;
    __shared__ int red[256];
    int base = t * N_;
    if (tid < 128) z[t * 128 + tid] = 0.0f;   // folded zinit
    int* pp = part + t * NB_ * N_;
    int vals[20];
    int sum = 0;
#pragma unroll
    for (int j = 0; j < 20; ++j) {
        int i = tid * 20 + j;
        int c = 0;
        if (i < N_) {
#pragma unroll
            for (int s = 0; s < NB_; ++s) c += pp[s * N_ + i];
            dinv[base + i] = rsqrtf((float)(c + 1));  // +1 self-loop
        }
        vals[j] = sum;
        sum += c;
    }
    red[tid] = sum;
    __syncthreads();
    for (int off = 1; off < 256; off <<= 1) {
        int v = (tid >= off) ? red[tid - off] : 0;
        __syncthreads();
        red[tid] += v;
        __syncthreads();
    }
    int prev = (tid > 0) ? red[tid - 1] : 0;
#pragma unroll
    for (int j = 0; j < 20; ++j) {
        int i = tid * 20 + j;
        if (i < N_) {
            int start = prev + vals[j];
            ptr[base + i] = start;
            int run = start;
#pragma unroll
            for (int s = 0; s < NB_; ++s) {
                int c = pp[s * N_ + i];
                pp[s * N_ + i] = run;
                run += c;
            }
        }
    }
}

__global__ __launch_bounds__(256) void k_scatter(const int* __restrict__ ei,
                                                 const int* __restrict__ part,
                                                 uint16_t* __restrict__ col) {
    __shared__ int cur[N_];
    int blk = blockIdx.x;
    int t = blk & 31, seg = blk >> 5;
    int tid = threadIdx.x;
    const int* off = part + (t * NB_ + seg) * N_;
    for (int i = tid * 4; i < N_; i += 1024) *(int4*)&cur[i] = *(const int4*)&off[i];
    __syncthreads();
    const int* src = ei + (size_t)t * 2 * E_ + seg * EPS_;
    const int* dst = src + E_;
    uint16_t* cl = col + (size_t)t * E_;
    for (int e = tid * 4; e < EPS_; e += 1024) {
        int4 s4 = *(const int4*)&src[e];
        int4 d4 = *(const int4*)&dst[e];
        cl[atomicAdd(&cur[d4.x], 1)] = (uint16_t)s4.x;
        cl[atomicAdd(&cur[d4.y], 1)] = (uint16_t)s4.y;
        cl[atomicAdd(&cur[d4.z], 1)] = (uint16_t)s4.z;
        cl[atomicAdd(&cur[d4.w], 1)] = (uint16_t)s4.w;
    }
}

// ---------------- weight prep: Wt[l][c][k] = (f16)W_l[k][c] ----------------
__global__ __launch_bounds__(256) void k_wprep(const float* __restrict__ W0,
                                               const float* __restrict__ W1,
                                               const float* __restrict__ W2,
                                               f16* __restrict__ Wt) {
    const float* W = (blockIdx.x == 0) ? W0 : (blockIdx.x == 1) ? W1 : W2;
    f16* dst = Wt + blockIdx.x * 16384;
    for (int idx = threadIdx.x; idx < 16384; idx += 256) {
        int c = idx >> 7, k = idx & 127;
        dst[idx] = (f16)W[k * 128 + c];
    }
}

// ---------------- MFMA GEMM ----------------
template <bool F32IN>
__global__ __launch_bounds__(256) void k_gemm(const void* __restrict__ in_,
                                              const f16* __restrict__ Wt,  // [c][k]
                                              const float* __restrict__ dinv,
                                              f16* __restrict__ g) {
    __shared__ f16 Ws[128 * LDA];
    __shared__ f16 As[64 * LDA];
    int b = blockIdx.x;
    int t = b & 31;
    int r0 = (b >> 5) * 64;
    int tid = threadIdx.x;

    {
        int c = tid >> 1, hf = tid & 1;
        const f16* src = Wt + c * 128 + hf * 64;
        f16* dst = Ws + c * LDA + hf * 64;
#pragma unroll
        for (int j = 0; j < 8; ++j) *(f16x8*)&dst[j * 8] = *(const f16x8*)&src[j * 8];
    }
    {
        int r = tid >> 2, kq = (tid & 3) * 32;
        bool valid = (r0 + r) < N_;
        f16* dst = As + r * LDA + kq;
        if (F32IN) {
            const float* src = (const float*)in_ + ((size_t)(t * N_ + r0 + r)) * H_ + kq;
#pragma unroll
            for (int j = 0; j < 8; ++j) {
                float4 v = valid ? *(const float4*)&src[j * 4] : make_float4(0.f, 0.f, 0.f, 0.f);
                dst[j * 4 + 0] = (f16)v.x;
                dst[j * 4 + 1] = (f16)v.y;
                dst[j * 4 + 2] = (f16)v.z;
                dst[j * 4 + 3] = (f16)v.w;
            }
        } else {
            const f16* src = (const f16*)in_ + ((size_t)(t * N_ + r0 + r)) * H_ + kq;
#pragma unroll
            for (int j = 0; j < 4; ++j) {
                f16x8 v = {};
                if (valid) v = *(const f16x8*)&src[j * 8];
                *(f16x8*)&dst[j * 8] = v;
            }
        }
    }
    __syncthreads();

    int w = tid >> 6, lane = tid & 63;
    int m = lane & 15, q = lane >> 4;
    int rw = w * 16;
    f32x4 acc[8];
#pragma unroll
    for (int n = 0; n < 8; ++n) acc[n] = (f32x4){0.f, 0.f, 0.f, 0.f};

#pragma unroll
    for (int kb = 0; kb < 4; ++kb) {
        f16x8 aF = *(const f16x8*)&As[(rw + m) * LDA + kb * 32 + q * 8];
#pragma unroll
        for (int n = 0; n < 8; ++n) {
            f16x8 bF = *(const f16x8*)&Ws[(n * 16 + m) * LDA + kb * 32 + q * 8];
            acc[n] = __builtin_amdgcn_mfma_f32_16x16x32_f16(aF, bF, acc[n], 0, 0, 0);
        }
    }
    __syncthreads();

#pragma unroll
    for (int i = 0; i < 4; ++i) {
        int rr = rw + q * 4 + i;
        int gr = r0 + rr;
        float d = dinv[t * N_ + (gr < N_ ? gr : N_ - 1)];
#pragma unroll
        for (int n = 0; n < 8; ++n)
            As[rr * LDA + n * 16 + m] = (f16)(acc[n][i] * d);
    }
    __syncthreads();
    {
        int r = tid >> 2, kq = (tid & 3) * 32;
        if (r0 + r < N_) {
            f16* dst = g + ((size_t)(t * N_ + r0 + r)) * H_ + kq;
            const f16* src = As + r * LDA + kq;
#pragma unroll
            for (int j = 0; j < 4; ++j) *(f16x8*)&dst[j * 8] = *(const f16x8*)&src[j * 8];
        }
    }
}

// ---------------- CSR gather + epilogue: unroll-2, 8 gathers in flight ----------------
__global__ __launch_bounds__(256) void k_aggr(const int* __restrict__ ptr,
                                              const uint16_t* __restrict__ col,
                                              const f16* __restrict__ g,
                                              const float* __restrict__ dinv,
                                              const float* __restrict__ b,
                                              f16* __restrict__ out) {
    __shared__ f16 sh[4 * 128];
    int blk = blockIdx.x;
    int t = blk & 31;
    int w = threadIdx.x >> 6;
    int n = (blk >> 5) * 4 + w;
    int lane = threadIdx.x & 63;
    int q = lane >> 4, m = lane & 15;
    int base = t * N_;
    int begin = ptr[base + n];
    int end = (n == N_ - 1) ? E_ : ptr[base + n + 1];
    const f16* gg = g + (size_t)base * H_;
    const uint16_t* cl = col + (size_t)t * E_;
    f16x8 acc0 = {}, acc1 = {};
    if (q == 0) acc0 = *(const f16x8*)&gg[(size_t)n * H_ + m * 8];  // self-loop
    int i = begin + q;
    for (; i + 4 < end; i += 8) {
        int s0 = cl[i];
        int s1 = cl[i + 4];
        f16x8 v0 = *(const f16x8*)&gg[(size_t)s0 * H_ + m * 8];
        f16x8 v1 = *(const f16x8*)&gg[(size_t)s1 * H_ + m * 8];
        acc0 += v0;
        acc1 += v1;
    }
    if (i < end) {
        int s = cl[i];
        acc0 += *(const f16x8*)&gg[(size_t)s * H_ + m * 8];
    }
    acc0 += acc1;
    union { f16x8 h; int i32[4]; } u;
    u.h = acc0;
#pragma unroll
    for (int j = 0; j < 4; ++j) {
        u.i32[j] = addpk(u.i32[j], __shfl(u.i32[j], lane ^ 16, 64));
        u.i32[j] = addpk(u.i32[j], __shfl(u.i32[j], lane ^ 32, 64));
    }
    if (q == 0) *(f16x8*)&sh[w * 128 + m * 8] = u.h;
    __syncthreads();
    int c = lane * 2;
    float d = dinv[base + n];
    f16x2 hv = *(const f16x2*)&sh[w * 128 + c];
    float v0 = fast_tanh(d * (float)hv[0] + b[c + 0]);
    float v1 = fast_tanh(d * (float)hv[1] + b[c + 1]);
    f16x2 o = {(f16)v0, (f16)v1};
    *(f16x2*)&out[((size_t)base + n) * H_ + c] = o;
}

// ---------------- node-sum: z[t][c] = sum_n h[t][n][c] ----------------
__global__ __launch_bounds__(256) void k_reduce(const f16* __restrict__ h, float* __restrict__ z) {
    int t = blockIdx.x, seg = blockIdx.y;
    int tid = threadIdx.x;
    int rg = tid >> 5;
    int c = (tid & 31) * 4;
    const f16* p = h + (size_t)t * N_ * H_;
    float4 acc = make_float4(0.f, 0.f, 0.f, 0.f);
    int n0 = seg * 500;
    for (int n = n0 + rg; n < n0 + 500; n += 8) {
        f16x4 v = *(const f16x4*)&p[(size_t)n * H_ + c];
        acc.x += (float)v[0]; acc.y += (float)v[1]; acc.z += (float)v[2]; acc.w += (float)v[3];
    }
    __shared__ float4 part[256];
    part[tid] = acc;
    __syncthreads();
    if (rg == 0) {
        float4 s = part[tid];
#pragma unroll
        for (int j = 1; j < 8; ++j) {
            float4 v = part[(j << 5) + tid];
            s.x += v.x; s.y += v.y; s.z += v.z; s.w += v.w;
        }
        atomicAdd(&z[t * H_ + c + 0], s.x);
        atomicAdd(&z[t * H_ + c + 1], s.y);
        atomicAdd(&z[t * H_ + c + 2], s.z);
        atomicAdd(&z[t * H_ + c + 3], s.w);
    }
}

// ---------------- head stage 1: q,k,v ----------------
__global__ __launch_bounds__(128) void k_qkv(const float* __restrict__ z,
                                             const float* __restrict__ Wq, const float* __restrict__ bq,
                                             const float* __restrict__ Wk, const float* __restrict__ bk,
                                             const float* __restrict__ Wv, const float* __restrict__ bv,
                                             float* __restrict__ q, float* __restrict__ k,
                                             float* __restrict__ v) {
    int t = blockIdx.x, c = threadIdx.x;
    __shared__ float zs[128];
    zs[c] = z[t * 128 + c];
    __syncthreads();
    float aq = bq[c], ak = bk[c], av = bv[c];
    for (int kk = 0; kk < 128; ++kk) {
        float zv = zs[kk];
        aq += zv * Wq[(kk << 7) + c];
        ak += zv * Wk[(kk << 7) + c];
        av += zv * Wv[(kk << 7) + c];
    }
    q[t * 128 + c] = aq;
    k[t * 128 + c] = ak;
    v[t * 128 + c] = av;
}

// ---------------- head stage 2 ----------------
__global__ __launch_bounds__(256) void k_attnmid(
    const float* __restrict__ q, const float* __restrict__ k, const float* __restrict__ v,
    const float* __restrict__ Wo, const float* __restrict__ bo,
    const float* __restrict__ g2, const float* __restrict__ beta2,
    const float* __restrict__ Wm1, const float* __restrict__ bm1,
    const float* __restrict__ Wm2, const float* __restrict__ bm2,
    float* __restrict__ xr) {
    int t = blockIdx.x, tid = threadIdx.x;
    __shared__ float Ks[32 * 128], Vs[32 * 128];
    __shared__ float qs[128], sc[8 * 32], xa[128], hid[512], ys[128];
    __shared__ float redA[128], redB[128];

    for (int i = tid; i < 32 * 128; i += 256) { Ks[i] = k[i]; Vs[i] = v[i]; }
    if (tid < 128) qs[tid] = q[t * 128 + tid];
    __syncthreads();

    {
        int h = tid >> 5, s = tid & 31;
        float d = 0.0f;
#pragma unroll
        for (int kk = 0; kk < 16; ++kk)
            d += qs[(h << 4) + kk] * Ks[(s << 7) + (h << 4) + kk];
        sc[tid] = d * 0.25f;
    }
    __syncthreads();
    if (tid < 8) {
        float m = -1e30f;
        for (int s = 0; s < 32; ++s) m = fmaxf(m, sc[(tid << 5) + s]);
        float l = 0.0f;
        for (int s = 0; s < 32; ++s) { float e = __expf(sc[(tid << 5) + s] - m); sc[(tid << 5) + s] = e; l += e; }
        float inv = 1.0f / l;
        for (int s = 0; s < 32; ++s) sc[(tid << 5) + s] *= inv;
    }
    __syncthreads();
    if (tid < 128) {
        int h = tid >> 4;
        float o = 0.0f;
        for (int s = 0; s < 32; ++s) o += sc[(h << 5) + s] * Vs[(s << 7) + tid];
        qs[tid] = o;
    }
    __syncthreads();
    if (tid < 128) {
        float a = bo[tid];
        for (int kk = 0; kk < 128; ++kk) a += qs[kk] * Wo[(kk << 7) + tid];
        xa[tid] = a;
    }
    __syncthreads();
    for (int j = tid; j < 512; j += 256) {
        float a = bm1[j];
        for (int kk = 0; kk < 128; ++kk) a += xa[kk] * Wm1[(kk << 9) + j];
        hid[j] = fmaxf(a, 0.0f);
    }
    __syncthreads();
    if (tid < 128) {
        float a = bm2[tid];
        for (int j = 0; j < 512; ++j) a += hid[j] * Wm2[(j << 7) + tid];
        ys[tid] = xa[tid] + a;
    }
    __syncthreads();
    if (tid < 128) { redA[tid] = ys[tid]; redB[tid] = ys[tid] * ys[tid]; }
    __syncthreads();
    for (int off = 64; off > 0; off >>= 1) {
        if (tid < off) { redA[tid] += redA[tid + off]; redB[tid] += redB[tid + off]; }
        __syncthreads();
    }
    float mu = redA[0] * (1.0f / 128.0f);
    float var = redB[0] * (1.0f / 128.0f) - mu * mu;
    float rs = rsqrtf(var + 1e-5f);
    if (tid < 128) {
        float yv = (ys[tid] - mu) * rs * g2[tid] + beta2[tid];
        xr[t * 128 + tid] = fmaxf(yv, 0.0f);
    }
}

// ---------------- head stage 3 ----------------
__global__ __launch_bounds__(128) void k_final(const float* __restrict__ xr,
                                               const float* __restrict__ Wl,
                                               const float* __restrict__ bl,
                                               float* __restrict__ out) {
    int tid = threadIdx.x;
    __shared__ float pooled[128];
    float s = 0.0f;
    for (int t = 0; t < 32; ++t) s += xr[t * 128 + tid];
    pooled[tid] = s;
    __syncthreads();
    if (tid < C_) {
        float a = bl[tid];
        for (int kk = 0; kk < 128; ++kk) a += pooled[kk] * Wl[kk * C_ + tid];
        out[tid] = a;
    }
}

extern "C" void kernel_launch(void* const* d_in, const int* in_sizes, int n_in,
                              void* d_out, int out_size, void* d_ws, size_t ws_size,
                              hipStream_t stream) {
    const float* x  = (const float*)d_in[0];
    const int*   ei = (const int*)d_in[1];
    const float* W0 = (const float*)d_in[2];  const float* b0 = (const float*)d_in[3];
    const float* W1 = (const float*)d_in[4];  const float* b1 = (const float*)d_in[5];
    const float* W2 = (const float*)d_in[6];  const float* b2 = (const float*)d_in[7];
    const float* Wq = (const float*)d_in[8];  const float* bq = (const float*)d_in[9];
    const float* Wk = (const float*)d_in[10]; const float* bk = (const float*)d_in[11];
    const float* Wv = (const float*)d_in[12]; const float* bv = (const float*)d_in[13];
    const float* Wo = (const float*)d_in[14]; const float* bo = (const float*)d_in[15];
    const float* g2 = (const float*)d_in[16]; const float* beta2 = (const float*)d_in[17];
    const float* Wm1 = (const float*)d_in[18]; const float* bm1 = (const float*)d_in[19];
    const float* Wm2 = (const float*)d_in[20]; const float* bm2 = (const float*)d_in[21];
    const float* Wl = (const float*)d_in[22]; const float* bl = (const float*)d_in[23];
    float* outp = (float*)d_out;

    const size_t BIG = (size_t)T_ * N_ * H_;
    char* ws = (char*)d_ws;
    float*    dinv = (float*)(ws);
    int*      ptr  = (int*)(ws + 640000);
    uint16_t* col  = (uint16_t*)(ws + 1280000);
    f16*      Wt   = (f16*)(ws + 6400000);
    f16*      P16  = (f16*)(ws + 6498304);
    f16*      Q16  = P16 + BIG;
    float*    z    = (float*)(Q16 + BIG);
    float*    zq   = z + 4096;
    float*    zk   = zq + 4096;
    float*    zv   = zk + 4096;
    float*    xr   = zv + 4096;
    int*      part = (int*)P16;   // CSR partials alias P16 (used only before first gemm)

    k_wprep<<<3, 256, 0, stream>>>(W0, W1, W2, Wt);
    k_count<<<NB_ * 32, 256, 0, stream>>>(ei, part);
    k_scan<<<T_, 256, 0, stream>>>(part, ptr, dinv, z);
    k_scatter<<<NB_ * 32, 256, 0, stream>>>(ei, part, col);

    const float* bl_[3] = {b0, b1, b2};
    k_gemm<true><<<79 * 32, 256, 0, stream>>>(x, Wt, dinv, P16);
    k_aggr<<<(N_ / 4) * 32, 256, 0, stream>>>(ptr, col, P16, dinv, bl_[0], Q16);
    k_gemm<false><<<79 * 32, 256, 0, stream>>>(Q16, Wt + 16384, dinv, P16);
    k_aggr<<<(N_ / 4) * 32, 256, 0, stream>>>(ptr, col, P16, dinv, bl_[1], Q16);
    k_gemm<false><<<79 * 32, 256, 0, stream>>>(Q16, Wt + 32768, dinv, P16);
    k_aggr<<<(N_ / 4) * 32, 256, 0, stream>>>(ptr, col, P16, dinv, bl_[2], Q16);

    k_reduce<<<dim3(T_, 10), 256, 0, stream>>>(Q16, z);

    k_qkv<<<T_, 128, 0, stream>>>(z, Wq, bq, Wk, bk, Wv, bv, zq, zk, zv);
    k_attnmid<<<T_, 256, 0, stream>>>(zq, zk, zv, Wo, bo, g2, beta2,
                                      Wm1, bm1, Wm2, bm2, xr);
    k_final<<<1, 128, 0, stream>>>(xr, Wl, bl, outp);
}

// Round 10
// 646.832 us; speedup vs baseline: 21.4567x; 1.0002x over previous
//
#include <hip/hip_runtime.h>
#include <cstdint>

#define T_ 32
#define N_ 5000
#define E_ 80000
#define H_ 128
#define HD_ 512
#define C_ 10

typedef _Float16 f16;
typedef f16 f16x8 __attribute__((ext_vector_type(8)));
typedef f16 f16x4 __attribute__((ext_vector_type(4)));
typedef f16 f16x2 __attribute__((ext_vector_type(2)));
typedef float f32x4 __attribute__((ext_vector_type(4)));

#define LDA 136   // padded LDS leading dim in f16
#define NB_ 8     // CSR-build blocks per graph
#define EPS_ (E_ / NB_)  // 10000 edges per block
#define STRIPS 16 // gemm row-strips per graph

__device__ inline int addpk(int a, int b) {
    f16x2 x = __builtin_bit_cast(f16x2, a);
    f16x2 y = __builtin_bit_cast(f16x2, b);
    f16x2 r = x + y;
    return __builtin_bit_cast(int, r);
}

__device__ inline float fast_tanh(float x) {
    return 1.0f - 2.0f / (__expf(2.0f * x) + 1.0f);
}

// ---------------- CSR build, LDS-atomic (no global atomics) ----------------
__global__ __launch_bounds__(256) void k_count(const int* __restrict__ ei, int* __restrict__ part) {
    __shared__ int cnt[N_];
    int blk = blockIdx.x;
    int t = blk & 31, seg = blk >> 5;
    int tid = threadIdx.x;
    for (int i = tid; i < N_; i += 256) cnt[i] = 0;
    __syncthreads();
    const int* dst = ei + (size_t)t * 2 * E_ + E_ + seg * EPS_;
    for (int e = tid * 4; e < EPS_; e += 1024) {
        int4 d = *(const int4*)&dst[e];
        atomicAdd(&cnt[d.x], 1);
        atomicAdd(&cnt[d.y], 1);
        atomicAdd(&cnt[d.z], 1);
        atomicAdd(&cnt[d.w], 1);
    }
    __syncthreads();
    int* p = part + (t * NB_ + seg) * N_;
    for (int i = tid * 4; i < N_; i += 1024) *(int4*)&p[i] = *(const int4*)&cnt[i];
}

__global__ __launch_bounds__(256) void k_scan(int* __restrict__ part, int* __restrict__ ptr,
                                              float* __restrict__ dinv, float* __restrict__ z) {
    int t = blockIdx.x, tid = threadIdx.x;
    __shared__ int red[256];
    int base = t * N_;
    if (tid < 128) z[t * 128 + tid] = 0.0f;   // folded zinit
    int* pp = part + t * NB_ * N_;
    int vals[20];
    int sum = 0;
#pragma unroll
    for (int j = 0; j < 20; ++j) {
        int i = tid * 20 + j;
        int c = 0;
        if (i < N_) {
#pragma unroll
            for (int s = 0; s < NB_; ++s) c += pp[s * N_ + i];
            dinv[base + i] = rsqrtf((float)(c + 1));  // +1 self-loop
        }
        vals[j] = sum;
        sum += c;
    }
    red[tid] = sum;
    __syncthreads();
    for (int off = 1; off < 256; off <<= 1) {
        int v = (tid >= off) ? red[tid - off] : 0;
        __syncthreads();
        red[tid] += v;
        __syncthreads();
    }
    int prev = (tid > 0) ? red[tid - 1] : 0;
#pragma unroll
    for (int j = 0; j < 20; ++j) {
        int i = tid * 20 + j;
        if (i < N_) {
            int start = prev + vals[j];
            ptr[base + i] = start;
            int run = start;
#pragma unroll
            for (int s = 0; s < NB_; ++s) {
                int c = pp[s * N_ + i];
                pp[s * N_ + i] = run;
                run += c;
            }
        }
    }
}

__global__ __launch_bounds__(256) void k_scatter(const int* __restrict__ ei,
                                                 const int* __restrict__ part,
                                                 uint16_t* __restrict__ col) {
    __shared__ int cur[N_];
    int blk = blockIdx.x;
    int t = blk & 31, seg = blk >> 5;
    int tid = threadIdx.x;
    const int* off = part + (t * NB_ + seg) * N_;
    for (int i = tid * 4; i < N_; i += 1024) *(int4*)&cur[i] = *(const int4*)&off[i];
    __syncthreads();
    const int* src = ei + (size_t)t * 2 * E_ + seg * EPS_;
    const int* dst = src + E_;
    uint16_t* cl = col + (size_t)t * E_;
    for (int e = tid * 4; e < EPS_; e += 1024) {
        int4 s4 = *(const int4*)&src[e];
        int4 d4 = *(const int4*)&dst[e];
        cl[atomicAdd(&cur[d4.x], 1)] = (uint16_t)s4.x;
        cl[atomicAdd(&cur[d4.y], 1)] = (uint16_t)s4.y;
        cl[atomicAdd(&cur[d4.z], 1)] = (uint16_t)s4.z;
        cl[atomicAdd(&cur[d4.w], 1)] = (uint16_t)s4.w;
    }
}

// ---------------- weight prep: Wt[l][c][k] = (f16)W_l[k][c] ----------------
__global__ __launch_bounds__(256) void k_wprep(const float* __restrict__ W0,
                                               const float* __restrict__ W1,
                                               const float* __restrict__ W2,
                                               f16* __restrict__ Wt) {
    const float* W = (blockIdx.x == 0) ? W0 : (blockIdx.x == 1) ? W1 : W2;
    f16* dst = Wt + blockIdx.x * 16384;
    for (int idx = threadIdx.x; idx < 16384; idx += 256) {
        int c = idx >> 7, k = idx & 127;
        dst[idx] = (f16)W[k * 128 + c];
    }
}

// ---------------- MFMA GEMM v3: W staged once, loop over row tiles ----------------
template <bool F32IN>
__global__ __launch_bounds__(256) void k_gemm(const void* __restrict__ in_,
                                              const f16* __restrict__ Wt,  // [c][k]
                                              const float* __restrict__ dinv,
                                              f16* __restrict__ g) {
    __shared__ f16 Ws[128 * LDA];
    __shared__ f16 As[64 * LDA];
    int b = blockIdx.x;
    int t = b & 31;
    int strip = b >> 5;
    int tid = threadIdx.x;

    // stage Wt -> Ws ONCE (first barrier is inside the tile loop)
    {
        int c = tid >> 1, hf = tid & 1;
        const f16* src = Wt + c * 128 + hf * 64;
        f16* dst = Ws + c * LDA + hf * 64;
#pragma unroll
        for (int j = 0; j < 8; ++j) *(f16x8*)&dst[j * 8] = *(const f16x8*)&src[j * 8];
    }

    int w = tid >> 6, lane = tid & 63;
    int m = lane & 15, q = lane >> 4;
    int rw = w * 16;
    int sr = tid >> 2, skq = (tid & 3) * 32;   // staging row / k-quarter

    for (int tile = strip; tile < 79; tile += STRIPS) {
        int r0 = tile * 64;
        // stage A
        {
            bool valid = (r0 + sr) < N_;
            f16* dst = As + sr * LDA + skq;
            if (F32IN) {
                const float* src = (const float*)in_ + ((size_t)(t * N_ + r0 + sr)) * H_ + skq;
#pragma unroll
                for (int j = 0; j < 8; ++j) {
                    float4 v = valid ? *(const float4*)&src[j * 4] : make_float4(0.f, 0.f, 0.f, 0.f);
                    dst[j * 4 + 0] = (f16)v.x;
                    dst[j * 4 + 1] = (f16)v.y;
                    dst[j * 4 + 2] = (f16)v.z;
                    dst[j * 4 + 3] = (f16)v.w;
                }
            } else {
                const f16* src = (const f16*)in_ + ((size_t)(t * N_ + r0 + sr)) * H_ + skq;
#pragma unroll
                for (int j = 0; j < 4; ++j) {
                    f16x8 v = {};
                    if (valid) v = *(const f16x8*)&src[j * 8];
                    *(f16x8*)&dst[j * 8] = v;
                }
            }
        }
        __syncthreads();  // A (and Ws on first iter) visible

        f32x4 acc[8];
#pragma unroll
        for (int n = 0; n < 8; ++n) acc[n] = (f32x4){0.f, 0.f, 0.f, 0.f};
#pragma unroll
        for (int kb = 0; kb < 4; ++kb) {
            f16x8 aF = *(const f16x8*)&As[(rw + m) * LDA + kb * 32 + q * 8];
#pragma unroll
            for (int n = 0; n < 8; ++n) {
                f16x8 bF = *(const f16x8*)&Ws[(n * 16 + m) * LDA + kb * 32 + q * 8];
                acc[n] = __builtin_amdgcn_mfma_f32_16x16x32_f16(aF, bF, acc[n], 0, 0, 0);
            }
        }
        __syncthreads();  // done reading As; reuse for epilogue

#pragma unroll
        for (int i = 0; i < 4; ++i) {
            int rr = rw + q * 4 + i;
            int gr = r0 + rr;
            float d = dinv[t * N_ + (gr < N_ ? gr : N_ - 1)];
#pragma unroll
            for (int n = 0; n < 8; ++n)
                As[rr * LDA + n * 16 + m] = (f16)(acc[n][i] * d);
        }
        __syncthreads();
        if (r0 + sr < N_) {
            f16* dst = g + ((size_t)(t * N_ + r0 + sr)) * H_ + skq;
            const f16* src = As + sr * LDA + skq;
#pragma unroll
            for (int j = 0; j < 4; ++j) *(f16x8*)&dst[j * 8] = *(const f16x8*)&src[j * 8];
        }
        __syncthreads();  // As free for next tile's staging
    }
}

// ---------------- CSR gather: coalesced index load + UNIFORM-exec shfl broadcast ----------------
// shfls are hoisted into wave-uniform control flow (ds_bpermute reads 0 from
// inactive source lanes — the divergent-loop version silently gathered row 0).
__global__ __launch_bounds__(256) void k_aggr(const int* __restrict__ ptr,
                                              const uint16_t* __restrict__ col,
                                              const f16* __restrict__ g,
                                              const float* __restrict__ dinv,
                                              const float* __restrict__ b,
                                              f16* __restrict__ out) {
    __shared__ f16 sh[4 * 128];
    int blk = blockIdx.x;
    int t = blk & 31;
    int w = threadIdx.x >> 6;
    int n = (blk >> 5) * 4 + w;
    int lane = threadIdx.x & 63;
    int q = lane >> 4, m = lane & 15;
    int base = t * N_;
    int begin = ptr[base + n];
    int end = (n == N_ - 1) ? E_ : ptr[base + n + 1];
    const f16* gg = g + (size_t)base * H_;
    const uint16_t* cl = col + (size_t)t * E_;
    f16x8 acc0 = {}, acc1 = {};
    if (q == 0) acc0 = *(const f16x8*)&gg[(size_t)n * H_ + m * 8];  // self-loop
    for (int cb = begin; cb < end; cb += 64) {
        int cnt = end - cb; if (cnt > 64) cnt = 64;           // wave-uniform
        int myidx = (lane < cnt) ? (int)cl[cb + lane] : 0;    // one coalesced load / 64 edges
        int iters = (cnt + 7) >> 3;                           // wave-uniform trip count
        for (int a = 0; a < iters; ++a) {
            int j0 = (a << 3) + q;   // <= 59
            int j1 = j0 + 4;         // <= 63
            int s0 = __shfl(myidx, j0, 64);  // all 64 lanes active here
            int s1 = __shfl(myidx, j1, 64);
            if (j0 < cnt) acc0 += *(const f16x8*)&gg[(size_t)s0 * H_ + m * 8];
            if (j1 < cnt) acc1 += *(const f16x8*)&gg[(size_t)s1 * H_ + m * 8];
        }
    }
    acc0 += acc1;
    union { f16x8 h; int i32[4]; } u;
    u.h = acc0;
#pragma unroll
    for (int j = 0; j < 4; ++j) {
        u.i32[j] = addpk(u.i32[j], __shfl(u.i32[j], lane ^ 16, 64));
        u.i32[j] = addpk(u.i32[j], __shfl(u.i32[j], lane ^ 32, 64));
    }
    if (q == 0) *(f16x8*)&sh[w * 128 + m * 8] = u.h;
    __syncthreads();
    int c = lane * 2;
    float d = dinv[base + n];
    f16x2 hv = *(const f16x2*)&sh[w * 128 + c];
    float v0 = fast_tanh(d * (float)hv[0] + b[c + 0]);
    float v1 = fast_tanh(d * (float)hv[1] + b[c + 1]);
    f16x2 o = {(f16)v0, (f16)v1};
    *(f16x2*)&out[((size_t)base + n) * H_ + c] = o;
}

// ---------------- node-sum: z[t][c] = sum_n h[t][n][c] ----------------
__global__ __launch_bounds__(256) void k_reduce(const f16* __restrict__ h, float* __restrict__ z) {
    int t = blockIdx.x, seg = blockIdx.y;
    int tid = threadIdx.x;
    int rg = tid >> 5;
    int c = (tid & 31) * 4;
    const f16* p = h + (size_t)t * N_ * H_;
    float4 acc = make_float4(0.f, 0.f, 0.f, 0.f);
    int n0 = seg * 500;
    for (int n = n0 + rg; n < n0 + 500; n += 8) {
        f16x4 v = *(const f16x4*)&p[(size_t)n * H_ + c];
        acc.x += (float)v[0]; acc.y += (float)v[1]; acc.z += (float)v[2]; acc.w += (float)v[3];
    }
    __shared__ float4 part[256];
    part[tid] = acc;
    __syncthreads();
    if (rg == 0) {
        float4 s = part[tid];
#pragma unroll
        for (int j = 1; j < 8; ++j) {
            float4 v = part[(j << 5) + tid];
            s.x += v.x; s.y += v.y; s.z += v.z; s.w += v.w;
        }
        atomicAdd(&z[t * H_ + c + 0], s.x);
        atomicAdd(&z[t * H_ + c + 1], s.y);
        atomicAdd(&z[t * H_ + c + 2], s.z);
        atomicAdd(&z[t * H_ + c + 3], s.w);
    }
}

// ---------------- head stage 1: q,k,v ----------------
__global__ __launch_bounds__(128) void k_qkv(const float* __restrict__ z,
                                             const float* __restrict__ Wq, const float* __restrict__ bq,
                                             const float* __restrict__ Wk, const float* __restrict__ bk,
                                             const float* __restrict__ Wv, const float* __restrict__ bv,
                                             float* __restrict__ q, float* __restrict__ k,
                                             float* __restrict__ v) {
    int t = blockIdx.x, c = threadIdx.x;
    __shared__ float zs[128];
    zs[c] = z[t * 128 + c];
    __syncthreads();
    float aq = bq[c], ak = bk[c], av = bv[c];
    for (int kk = 0; kk < 128; ++kk) {
        float zv = zs[kk];
        aq += zv * Wq[(kk << 7) + c];
        ak += zv * Wk[(kk << 7) + c];
        av += zv * Wv[(kk << 7) + c];
    }
    q[t * 128 + c] = aq;
    k[t * 128 + c] = ak;
    v[t * 128 + c] = av;
}

// ---------------- head stage 2 ----------------
__global__ __launch_bounds__(256) void k_attnmid(
    const float* __restrict__ q, const float* __restrict__ k, const float* __restrict__ v,
    const float* __restrict__ Wo, const float* __restrict__ bo,
    const float* __restrict__ g2, const float* __restrict__ beta2,
    const float* __restrict__ Wm1, const float* __restrict__ bm1,
    const float* __restrict__ Wm2, const float* __restrict__ bm2,
    float* __restrict__ xr) {
    int t = blockIdx.x, tid = threadIdx.x;
    __shared__ float Ks[32 * 128], Vs[32 * 128];
    __shared__ float qs[128], sc[8 * 32], xa[128], hid[512], ys[128];
    __shared__ float redA[128], redB[128];

    for (int i = tid; i < 32 * 128; i += 256) { Ks[i] = k[i]; Vs[i] = v[i]; }
    if (tid < 128) qs[tid] = q[t * 128 + tid];
    __syncthreads();

    {
        int h = tid >> 5, s = tid & 31;
        float d = 0.0f;
#pragma unroll
        for (int kk = 0; kk < 16; ++kk)
            d += qs[(h << 4) + kk] * Ks[(s << 7) + (h << 4) + kk];
        sc[tid] = d * 0.25f;
    }
    __syncthreads();
    if (tid < 8) {
        float m = -1e30f;
        for (int s = 0; s < 32; ++s) m = fmaxf(m, sc[(tid << 5) + s]);
        float l = 0.0f;
        for (int s = 0; s < 32; ++s) { float e = __expf(sc[(tid << 5) + s] - m); sc[(tid << 5) + s] = e; l += e; }
        float inv = 1.0f / l;
        for (int s = 0; s < 32; ++s) sc[(tid << 5) + s] *= inv;
    }
    __syncthreads();
    if (tid < 128) {
        int h = tid >> 4;
        float o = 0.0f;
        for (int s = 0; s < 32; ++s) o += sc[(h << 5) + s] * Vs[(s << 7) + tid];
        qs[tid] = o;
    }
    __syncthreads();
    if (tid < 128) {
        float a = bo[tid];
        for (int kk = 0; kk < 128; ++kk) a += qs[kk] * Wo[(kk << 7) + tid];
        xa[tid] = a;
    }
    __syncthreads();
    for (int j = tid; j < 512; j += 256) {
        float a = bm1[j];
        for (int kk = 0; kk < 128; ++kk) a += xa[kk] * Wm1[(kk << 9) + j];
        hid[j] = fmaxf(a, 0.0f);
    }
    __syncthreads();
    if (tid < 128) {
        float a = bm2[tid];
        for (int j = 0; j < 512; ++j) a += hid[j] * Wm2[(j << 7) + tid];
        ys[tid] = xa[tid] + a;
    }
    __syncthreads();
    if (tid < 128) { redA[tid] = ys[tid]; redB[tid] = ys[tid] * ys[tid]; }
    __syncthreads();
    for (int off = 64; off > 0; off >>= 1) {
        if (tid < off) { redA[tid] += redA[tid + off]; redB[tid] += redB[tid + off]; }
        __syncthreads();
    }
    float mu = redA[0] * (1.0f / 128.0f);
    float var = redB[0] * (1.0f / 128.0f) - mu * mu;
    float rs = rsqrtf(var + 1e-5f);
    if (tid < 128) {
        float yv = (ys[tid] - mu) * rs * g2[tid] + beta2[tid];
        xr[t * 128 + tid] = fmaxf(yv, 0.0f);
    }
}

// ---------------- head stage 3 ----------------
__global__ __launch_bounds__(128) void k_final(const float* __restrict__ xr,
                                               const float* __restrict__ Wl,
                                               const float* __restrict__ bl,
                                               float* __restrict__ out) {
    int tid = threadIdx.x;
    __shared__ float pooled[128];
    float s = 0.0f;
    for (int t = 0; t < 32; ++t) s += xr[t * 128 + tid];
    pooled[tid] = s;
    __syncthreads();
    if (tid < C_) {
        float a = bl[tid];
        for (int kk = 0; kk < 128; ++kk) a += pooled[kk] * Wl[kk * C_ + tid];
        out[tid] = a;
    }
}

extern "C" void kernel_launch(void* const* d_in, const int* in_sizes, int n_in,
                              void* d_out, int out_size, void* d_ws, size_t ws_size,
                              hipStream_t stream) {
    const float* x  = (const float*)d_in[0];
    const int*   ei = (const int*)d_in[1];
    const float* W0 = (const float*)d_in[2];  const float* b0 = (const float*)d_in[3];
    const float* W1 = (const float*)d_in[4];  const float* b1 = (const float*)d_in[5];
    const float* W2 = (const float*)d_in[6];  const float* b2 = (const float*)d_in[7];
    const float* Wq = (const float*)d_in[8];  const float* bq = (const float*)d_in[9];
    const float* Wk = (const float*)d_in[10]; const float* bk = (const float*)d_in[11];
    const float* Wv = (const float*)d_in[12]; const float* bv = (const float*)d_in[13];
    const float* Wo = (const float*)d_in[14]; const float* bo = (const float*)d_in[15];
    const float* g2 = (const float*)d_in[16]; const float* beta2 = (const float*)d_in[17];
    const float* Wm1 = (const float*)d_in[18]; const float* bm1 = (const float*)d_in[19];
    const float* Wm2 = (const float*)d_in[20]; const float* bm2 = (const float*)d_in[21];
    const float* Wl = (const float*)d_in[22]; const float* bl = (const float*)d_in[23];
    float* outp = (float*)d_out;

    const size_t BIG = (size_t)T_ * N_ * H_;
    char* ws = (char*)d_ws;
    float*    dinv = (float*)(ws);
    int*      ptr  = (int*)(ws + 640000);
    uint16_t* col  = (uint16_t*)(ws + 1280000);
    f16*      Wt   = (f16*)(ws + 6400000);
    f16*      P16  = (f16*)(ws + 6498304);
    f16*      Q16  = P16 + BIG;
    float*    z    = (float*)(Q16 + BIG);
    float*    zq   = z + 4096;
    float*    zk   = zq + 4096;
    float*    zv   = zk + 4096;
    float*    xr   = zv + 4096;
    int*      part = (int*)P16;   // CSR partials alias P16 (used only before first gemm)

    k_wprep<<<3, 256, 0, stream>>>(W0, W1, W2, Wt);
    k_count<<<NB_ * 32, 256, 0, stream>>>(ei, part);
    k_scan<<<T_, 256, 0, stream>>>(part, ptr, dinv, z);
    k_scatter<<<NB_ * 32, 256, 0, stream>>>(ei, part, col);

    const float* bl_[3] = {b0, b1, b2};
    k_gemm<true><<<STRIPS * 32, 256, 0, stream>>>(x, Wt, dinv, P16);
    k_aggr<<<(N_ / 4) * 32, 256, 0, stream>>>(ptr, col, P16, dinv, bl_[0], Q16);
    k_gemm<false><<<STRIPS * 32, 256, 0, stream>>>(Q16, Wt + 16384, dinv, P16);
    k_aggr<<<(N_ / 4) * 32, 256, 0, stream>>>(ptr, col, P16, dinv, bl_[1], Q16);
    k_gemm<false><<<STRIPS * 32, 256, 0, stream>>>(Q16, Wt + 32768, dinv, P16);
    k_aggr<<<(N_ / 4) * 32, 256, 0, stream>>>(ptr, col, P16, dinv, bl_[2], Q16);

    k_reduce<<<dim3(T_, 10), 256, 0, stream>>>(Q16, z);

    k_qkv<<<T_, 128, 0, stream>>>(z, Wq, bq, Wk, bk, Wv, bv, zq, zk, zv);
    k_attnmid<<<T_, 256, 0, stream>>>(zq, zk, zv, Wo, bo, g2, beta2,
                                      Wm1, bm1, Wm2, bm2, xr);
    k_final<<<1, 128, 0, stream>>>(xr, Wl, bl, outp);
}